// Round 1
// baseline (250.516 us; speedup 1.0000x reference)
//
#include <hip/hip_runtime.h>
#include <math.h>

#define BATCH 8
#define SEQ   2048
#define DIM   1024
#define HD    64
#define NROWS (BATCH * SEQ)   // 16384
#define CHUNK 256
#define NCHUNK 8              // SEQ / CHUNK
#define QTILE 64              // q rows per attention block
#define NQT   (SEQ / QTILE)   // 32
#define QSCALE 0.1803368801f  // 0.125 * log2(e): folded into Q so P = exp2(QK^T)

typedef __attribute__((ext_vector_type(8))) short bf16x8;  // 8 bf16 = 4 VGPRs
typedef __attribute__((ext_vector_type(4))) float f32x4;

__device__ __forceinline__ unsigned short f2bf(float f) {
    unsigned u = __float_as_uint(f);
    u = (u + 0x7FFFu + ((u >> 16) & 1u)) >> 16;   // RNE
    return (unsigned short)u;
}
// cheap half-up rounding (2 ops)
__device__ __forceinline__ unsigned short f2bf_hu(float f) {
    return (unsigned short)((__float_as_uint(f) + 0x8000u) >> 16);
}
__device__ __forceinline__ float fast_exp2(float x) {
#if __has_builtin(__builtin_amdgcn_exp2f)
    return __builtin_amdgcn_exp2f(x);
#else
    return exp2f(x);
#endif
}

// async global -> LDS DMA, 16 B per lane.  LDS dest = wave-uniform base + lane*16.
__device__ __forceinline__ void gld_lds16(const void* g, void* l) {
    __builtin_amdgcn_global_load_lds(
        (const __attribute__((address_space(1))) void*)g,
        (__attribute__((address_space(3))) void*)l, 16, 0, 0);
}

// Swizzled LDS tiles: global 16B-chunk g of row r stored at LDS chunk
// g ^ (r & (nchunk-1)); DMA encodes the permutation on the source address.
// MFMA frag reads then spread a quad's 16 lanes across all banks (2-way max).

// ---------------------------------------------------------------------------
// prep_w: Wt[mat][n][k] (bf16) <- W[k][n] (fp32).  grid (16,3), block 256.
// ---------------------------------------------------------------------------
__global__ __launch_bounds__(256)
void prep_w_kernel(const float* __restrict__ Wq, const float* __restrict__ Wk,
                   const float* __restrict__ Wv, unsigned short* __restrict__ Wt)
{
    const int mat = blockIdx.y;
    const float* __restrict__ W = (mat == 0) ? Wq : (mat == 1) ? Wk : Wv;
    const int k0 = blockIdx.x * 64;
    __shared__ float T[64][65];
    const int t = threadIdx.x;
    #pragma unroll
    for (int i = 0; i < 16; ++i) {
        const int idx = t + i * 256;
        T[idx >> 6][idx & 63] = W[(size_t)(k0 + (idx >> 6)) * HD + (idx & 63)];
    }
    __syncthreads();
    const int n = t >> 2;
    const int c = t & 3;
    union { unsigned short h[16]; uint4 v[2]; } buf;
    #pragma unroll
    for (int j = 0; j < 16; ++j) buf.h[j] = f2bf(T[c * 16 + j][n]);
    unsigned short* dst = Wt + ((size_t)mat * HD + n) * DIM + k0 + c * 16;
    *(uint4*)dst       = buf.v[0];
    *(uint4*)(dst + 8) = buf.v[1];
}

// ---------------------------------------------------------------------------
// qkv_mfma: tile 32 rows x 192 cols, BK=128 (8 barrier iterations).
// block 384 thr = 6 waves; wave w: rows (w&1)*16..+15, mat = w>>1 (4 acc).
// grid 512 (2 blocks/CU — grid-capped, so the x HBM load is SW-pipelined:
// iteration i+1's x tile is prefetched into VGPRs during compute of i).
// Q is pre-scaled by QSCALE.  Outputs: Q,K row-major bf16; V^T bf16.
// Tail: grid-stride zero of Oacc/Lacc/Cnt (stream-ordered before attn).
// ---------------------------------------------------------------------------
__global__ __launch_bounds__(384)
void qkv_mfma_kernel(const float* __restrict__ x,
                     const unsigned short* __restrict__ Wt,
                     const float* __restrict__ bq, const float* __restrict__ bk,
                     const float* __restrict__ bv,
                     unsigned short* __restrict__ Qg,
                     unsigned short* __restrict__ Kg,
                     unsigned short* __restrict__ Vtg,
                     float* __restrict__ Oacc,      // [16384][64] f32 (+Lacc after)
                     unsigned* __restrict__ Cnt)    // [256]
{
    __shared__ unsigned short Xs[32][128];    // 8 KB, swizzled chunks (key r&15)
    __shared__ unsigned short Ws[192][128];   // 48 KB, swizzled chunks

    const int t    = threadIdx.x;
    const int lane = t & 63;
    const int w    = t >> 6;         // 0..5
    const int col  = lane & 15;
    const int quad = lane >> 4;
    const int rh   = w & 1;          // 16-row half
    const int mat  = w >> 1;         // 0=Q, 1=K, 2=V
    const int row0 = blockIdx.x * 32;

    const int r4   = lane >> 4;      // 4 rows per DMA call (16 chunks/row)
    const int ch16 = lane & 15;

    f32x4 acc[4];
    #pragma unroll
    for (int i = 0; i < 4; ++i) acc[i] = (f32x4){0.f, 0.f, 0.f, 0.f};

    // x prefetch registers (threads 0..255 stage the X tile)
    const int xr  = t >> 3;          // row
    const int xc0 = t & 7;           // first of two 8-float chunks
    const float* __restrict__ xrow = &x[(size_t)(row0 + xr) * DIM];
    float4 xv[4];
    if (t < 256) {
        xv[0] = *(const float4*)(xrow + xc0 * 8);
        xv[1] = *(const float4*)(xrow + xc0 * 8 + 4);
        xv[2] = *(const float4*)(xrow + (xc0 + 8) * 8);
        xv[3] = *(const float4*)(xrow + (xc0 + 8) * 8 + 4);
    }

    for (int it = 0; it < 8; ++it) {
        const int k0 = it * 128;
        __syncthreads();   // previous compute done; Xs/Ws reusable
        // store prefetched X (fp32 -> bf16, half-up pair pack, swizzled)
        if (t < 256) {
            #pragma unroll
            for (int h = 0; h < 2; ++h) {
                const int g = xc0 + h * 8;
                const float4 v0 = xv[h * 2];
                const float4 v1 = xv[h * 2 + 1];
                uint4 o;
                o.x = ((__float_as_uint(v0.x) + 0x8000u) >> 16) | ((__float_as_uint(v0.y) + 0x8000u) & 0xFFFF0000u);
                o.y = ((__float_as_uint(v0.z) + 0x8000u) >> 16) | ((__float_as_uint(v0.w) + 0x8000u) & 0xFFFF0000u);
                o.z = ((__float_as_uint(v1.x) + 0x8000u) >> 16) | ((__float_as_uint(v1.y) + 0x8000u) & 0xFFFF0000u);
                o.w = ((__float_as_uint(v1.z) + 0x8000u) >> 16) | ((__float_as_uint(v1.w) + 0x8000u) & 0xFFFF0000u);
                *(uint4*)&Xs[xr][(g ^ (xr & 15)) * 8] = o;
            }
        }
        // W tile: 192 rows x 128 k via swizzled DMA (6 waves x 8 calls x 4 rows)
        #pragma unroll
        for (int ii = 0; ii < 8; ++ii) {
            const int rbase = w * 32 + ii * 4;
            const int r = rbase + r4;
            gld_lds16(&Wt[(size_t)r * DIM + k0 + (ch16 ^ (r & 15)) * 8], &Ws[rbase][0]);
        }
        __syncthreads();   // staging ready (drains W DMA + Xs stores)
        // prefetch next iteration's x while MFMAs run
        if (it < 7 && t < 256) {
            const float* xp = xrow + k0 + 128;
            xv[0] = *(const float4*)(xp + xc0 * 8);
            xv[1] = *(const float4*)(xp + xc0 * 8 + 4);
            xv[2] = *(const float4*)(xp + (xc0 + 8) * 8);
            xv[3] = *(const float4*)(xp + (xc0 + 8) * 8 + 4);
        }
        #pragma unroll
        for (int ks = 0; ks < 4; ++ks) {
            const int fswz = ((ks * 4 + quad) ^ col) * 8;   // frag rows ≡ col (mod 16)
            const bf16x8 a = *(const bf16x8*)&Xs[rh * 16 + col][fswz];
            #pragma unroll
            for (int nt = 0; nt < 4; ++nt) {
                const bf16x8 b = *(const bf16x8*)&Ws[mat * 64 + nt * 16 + col][fswz];
                acc[nt] = __builtin_amdgcn_mfma_f32_16x16x32_bf16(a, b, acc[nt], 0, 0, 0);
            }
        }
    }

    // Epilogue.  C layout: col = lane&15, row = quad*4 + r.
    const int b    = row0 / SEQ;
    const int s0   = (row0 % SEQ) + rh * 16 + quad * 4;
    const int grow = row0 + rh * 16 + quad * 4;
    const float* __restrict__ bias = (mat == 0) ? bq : (mat == 1) ? bk : bv;
    const float oscale = (mat == 0) ? QSCALE : 1.0f;   // fold softmax scale into Q
    #pragma unroll
    for (int nt = 0; nt < 4; ++nt) {
        const int nn = nt * 16 + col;
        const float bvv = bias[nn];
        if (mat < 2) {
            unsigned short* __restrict__ o = (mat == 0) ? Qg : Kg;
            #pragma unroll
            for (int r = 0; r < 4; ++r)
                o[(size_t)(grow + r) * HD + nn] = f2bf((acc[nt][r] + bvv) * oscale);
        } else {
            const unsigned lo = (unsigned)f2bf(acc[nt][0] + bvv) | ((unsigned)f2bf(acc[nt][1] + bvv) << 16);
            const unsigned hi = (unsigned)f2bf(acc[nt][2] + bvv) | ((unsigned)f2bf(acc[nt][3] + bvv) << 16);
            *(uint2*)&Vtg[((size_t)b * HD + nn) * SEQ + s0] = make_uint2(lo, hi);
        }
    }

    // zero the attention accumulators (Oacc + Lacc laid out contiguously)
    const float4 z4 = (float4){0.f, 0.f, 0.f, 0.f};
    const int nz = (NROWS * HD + NROWS) / 4;   // 266240 float4
    for (int i = blockIdx.x * 384 + t; i < nz; i += 512 * 384)
        ((float4*)Oacc)[i] = z4;
    if (blockIdx.x == 0 && t < BATCH * NQT)
        Cnt[t] = 0u;
}

// ---------------------------------------------------------------------------
// attn_part: split-key flash attention, no online max (scores bounded),
// P = exp2(QK^T) with scale folded into Q.  Partials accumulated in fp32 via
// device-scope atomicAdd; last chunk-block per (b,qt) normalizes + writes out.
// grid (8, 144): x = batch (XCD-aligned: linear id ≡ batch mod 8, so each
// XCD's L2 caches one batch's K/V), y = compacted (c, qt) triangle.
// block 256 thr (4 waves x 16 q rows), <=4 K-iters.
// ---------------------------------------------------------------------------
__global__ __launch_bounds__(256)
void attn_part_kernel(const unsigned short* __restrict__ Qg,
                      const unsigned short* __restrict__ Kg,
                      const unsigned short* __restrict__ Vtg,
                      float* __restrict__ Oacc,   // [16384][64] f32, zeroed
                      float* __restrict__ Lacc,   // [16384] f32, zeroed
                      unsigned* __restrict__ Cnt, // [256], zeroed
                      float* __restrict__ out)    // [16384][64] f32 final
{
    const int b = blockIdx.x;
    // decode compacted triangle: for chunk c, valid qt in [4c, 31]
    int y = blockIdx.y, c = 0;
    while (y >= 32 - 4 * c) { y -= 32 - 4 * c; ++c; }
    const int qt = y + 4 * c;

    __shared__ unsigned short Ks[64][64];     // [key][d], swizzled (key r&7)
    __shared__ unsigned short Vs[64][64];     // [d][key], swizzled
    __shared__ unsigned short Ps[4][16][76];  // per-wave P, A layout [m][key]
    __shared__ int isLast;

    const int t    = threadIdx.x;
    const int w    = t >> 6;
    const int lane = t & 63;
    const int col  = lane & 15;
    const int quad = lane >> 4;
    const int q0w  = qt * QTILE + w * 16;
    const size_t gq = (size_t)b * SEQ + q0w;

    const bf16x8 aq0 = *(const bf16x8*)&Qg[(gq + col) * HD + quad * 8];
    const bf16x8 aq1 = *(const bf16x8*)&Qg[(gq + col) * HD + 32 + quad * 8];

    f32x4 oacc[4];
    #pragma unroll
    for (int n = 0; n < 4; ++n) oacc[n] = (f32x4){0.f, 0.f, 0.f, 0.f};
    float lpart[4] = {0.f, 0.f, 0.f, 0.f};   // per-lane partial denominators

    const int kbeg   = c * CHUNK;
    const int kend   = min((c + 1) * CHUNK, (qt + 1) * QTILE);
    const int ntiles = (kend - kbeg + 63) >> 6;

    const int r8 = lane >> 3, ch = lane & 7;
    const int swzr = (ch ^ r8) * 8;
    const unsigned short* kgb = Kg  + (size_t)b * SEQ * HD;
    const unsigned short* vgb = Vtg + (size_t)b * HD * SEQ;

    for (int it = 0; it < ntiles; ++it) {
        const int j0 = kbeg + it * 64;
        __syncthreads();
        // stage K (8 KB) + V^T (8 KB): 4 waves x 2 calls x 8 rows each
        #pragma unroll
        for (int ii = 0; ii < 2; ++ii) {
            const int rb = w * 16 + ii * 8;
            gld_lds16(&kgb[(size_t)(j0 + rb + r8) * HD + swzr], &Ks[rb][0]);
            gld_lds16(&vgb[(size_t)(rb + r8) * SEQ + j0 + swzr], &Vs[rb][0]);
        }
        __syncthreads();

        if (j0 <= q0w + 15) {   // wave-uniform: skip fully-masked tiles
            // scores (log2 domain: Q carries 0.125*log2e)
            f32x4 scv[4];
            #pragma unroll
            for (int nt = 0; nt < 4; ++nt) {
                const int sw0 = (quad ^ (col & 7)) * 8;
                const int sw1 = ((4 + quad) ^ (col & 7)) * 8;
                const bf16x8 bk0 = *(const bf16x8*)&Ks[nt * 16 + col][sw0];
                const bf16x8 bk1 = *(const bf16x8*)&Ks[nt * 16 + col][sw1];
                f32x4 s = __builtin_amdgcn_mfma_f32_16x16x32_bf16(aq0, bk0, (f32x4){0.f,0.f,0.f,0.f}, 0, 0, 0);
                s = __builtin_amdgcn_mfma_f32_16x16x32_bf16(aq1, bk1, s, 0, 0, 0);
                scv[nt] = s;
            }
            const bool needmask = (j0 + 63 > q0w);
            #pragma unroll
            for (int r = 0; r < 4; ++r) {
                const int row = q0w + quad * 4 + r;
                #pragma unroll
                for (int nt = 0; nt < 4; ++nt) {
                    float s = scv[nt][r];
                    if (needmask)
                        s = (j0 + nt * 16 + col <= row) ? s : -INFINITY;
                    const float p = fast_exp2(s);   // exp2(-inf) = 0 handles mask
                    lpart[r] += p;
                    Ps[w][quad * 4 + r][nt * 16 + col] = f2bf_hu(p);  // same-wave LDS
                }
            }
            // PV: O += P V
            #pragma unroll
            for (int ks = 0; ks < 2; ++ks) {
                const bf16x8 ap = *(const bf16x8*)&Ps[w][col][ks * 32 + quad * 8];
                const int fswz = ((ks * 4 + quad) ^ (col & 7)) * 8;
                #pragma unroll
                for (int n = 0; n < 4; ++n) {
                    const bf16x8 bv2 = *(const bf16x8*)&Vs[n * 16 + col][fswz];
                    oacc[n] = __builtin_amdgcn_mfma_f32_16x16x32_bf16(ap, bv2, oacc[n], 0, 0, 0);
                }
            }
        }
    }

    // deferred 16-lane reduction of the denominators (once per kernel)
    #pragma unroll
    for (int r = 0; r < 4; ++r) {
        #pragma unroll
        for (int off = 1; off < 16; off <<= 1)
            lpart[r] += __shfl_xor(lpart[r], off, 64);
    }

    // epilogue: fp32 atomic accumulation (device-scope, coherent cross-XCD)
    const int qrow0 = qt * QTILE;
    float* __restrict__ Ob = Oacc + ((size_t)b * SEQ + qrow0) * HD;
    #pragma unroll
    for (int n = 0; n < 4; ++n)
        #pragma unroll
        for (int r = 0; r < 4; ++r)
            atomicAdd(&Ob[(w * 16 + quad * 4 + r) * HD + n * 16 + col], oacc[n][r]);
    if (col == 0) {
        float* lb = Lacc + (size_t)b * SEQ + qrow0 + w * 16;
        #pragma unroll
        for (int r = 0; r < 4; ++r)
            atomicAdd(&lb[quad * 4 + r], lpart[r]);
    }
    __threadfence();       // per-thread: all my atomics completed (vmcnt drain)
    __syncthreads();       // => all block atomics completed before the signal
    if (t == 0) {
        const int nchunks = (qt >> 2) + 1;   // chunks covering this q-tile
        isLast = (atomicAdd(&Cnt[b * NQT + qt], 1u) == (unsigned)(nchunks - 1));
    }
    __syncthreads();
    if (!isLast) return;

    // last chunk-block for (b,qt): normalize + write final fp32 output.
    // Agent-scope relaxed atomic loads bypass the (non-coherent) XCD L2 and
    // read the coherent point directly — no L2-invalidating acquire needed.
    const int r   = t >> 2;            // 0..63 (q row within tile)
    const int d0  = (t & 3) * 16;      // 16 dims per thread
    const size_t grow = (size_t)b * SEQ + qrow0 + r;
    const float L = __hip_atomic_load(&Lacc[grow], __ATOMIC_RELAXED,
                                      __HIP_MEMORY_SCOPE_AGENT);
    const float rL = 1.0f / L;
    float o[16];
    #pragma unroll
    for (int j = 0; j < 8; ++j) {
        const unsigned long long u = __hip_atomic_load(
            (const unsigned long long*)&Ob[r * HD + d0 + j * 2],
            __ATOMIC_RELAXED, __HIP_MEMORY_SCOPE_AGENT);
        o[j * 2]     = __uint_as_float((unsigned)u) * rL;
        o[j * 2 + 1] = __uint_as_float((unsigned)(u >> 32)) * rL;
    }
    float4* op = (float4*)&out[grow * HD + d0];
    op[0] = (float4){o[0],  o[1],  o[2],  o[3]};
    op[1] = (float4){o[4],  o[5],  o[6],  o[7]};
    op[2] = (float4){o[8],  o[9],  o[10], o[11]};
    op[3] = (float4){o[12], o[13], o[14], o[15]};
}

// ---------------------------------------------------------------------------
extern "C" void kernel_launch(void* const* d_in, const int* in_sizes, int n_in,
                              void* d_out, int out_size, void* d_ws, size_t ws_size,
                              hipStream_t stream) {
    const float* x  = (const float*)d_in[0];
    const float* Wq = (const float*)d_in[1];
    const float* bq = (const float*)d_in[2];
    const float* Wk = (const float*)d_in[3];
    const float* bk = (const float*)d_in[4];
    const float* Wv = (const float*)d_in[5];
    const float* bv = (const float*)d_in[6];
    float* out = (float*)d_out;

    unsigned short* Wt  = (unsigned short*)d_ws;          // [3][64][1024] bf16
    unsigned short* Qg  = Wt + (size_t)3 * HD * DIM;      // [16384][64] bf16 (pre-scaled)
    unsigned short* Kg  = Qg + (size_t)NROWS * HD;        // [16384][64] bf16
    unsigned short* Vtg = Kg + (size_t)NROWS * HD;        // [8][64][2048] bf16
    float* Oacc = (float*)(Vtg + (size_t)BATCH * HD * SEQ);  // [16384][64] f32
    float* Lacc = Oacc + (size_t)NROWS * HD;                 // [16384] f32
    unsigned* Cnt = (unsigned*)(Lacc + NROWS);               // [256] u32

    prep_w_kernel<<<dim3(16, 3), 256, 0, stream>>>(Wq, Wk, Wv, Wt);
    qkv_mfma_kernel<<<dim3(NROWS / 32), 384, 0, stream>>>(x, Wt, bq, bk, bv,
                                                          Qg, Kg, Vtg, Oacc, Cnt);
    attn_part_kernel<<<dim3(8, 144), 256, 0, stream>>>(Qg, Kg, Vtg,
                                                       Oacc, Lacc, Cnt, out);
}

// Round 2
// 151.393 us; speedup vs baseline: 1.6547x; 1.6547x over previous
//
#include <hip/hip_runtime.h>
#include <math.h>

#define BATCH 8
#define SEQ   2048
#define DIM   1024
#define HD    64
#define NROWS (BATCH * SEQ)   // 16384
#define CHUNK 256
#define NCHUNK 8              // SEQ / CHUNK
#define QTILE 64              // q rows per attention block
#define NQT   (SEQ / QTILE)   // 32
#define QSCALE 0.1803368801f  // 0.125 * log2(e): folded into Q so P = exp2(QK^T)

typedef __attribute__((ext_vector_type(8))) short bf16x8;  // 8 bf16 = 4 VGPRs
typedef __attribute__((ext_vector_type(4))) float f32x4;

__device__ __forceinline__ unsigned short f2bf(float f) {
    unsigned u = __float_as_uint(f);
    u = (u + 0x7FFFu + ((u >> 16) & 1u)) >> 16;   // RNE
    return (unsigned short)u;
}
// cheap half-up rounding (2 ops)
__device__ __forceinline__ unsigned short f2bf_hu(float f) {
    return (unsigned short)((__float_as_uint(f) + 0x8000u) >> 16);
}
__device__ __forceinline__ float fast_exp2(float x) {
#if __has_builtin(__builtin_amdgcn_exp2f)
    return __builtin_amdgcn_exp2f(x);
#else
    return exp2f(x);
#endif
}

// async global -> LDS DMA, 16 B per lane.  LDS dest = wave-uniform base + lane*16.
__device__ __forceinline__ void gld_lds16(const void* g, void* l) {
    __builtin_amdgcn_global_load_lds(
        (const __attribute__((address_space(1))) void*)g,
        (__attribute__((address_space(3))) void*)l, 16, 0, 0);
}

// pack 8 fp32 -> 8 bf16 (half-up) as one uint4
__device__ __forceinline__ uint4 pack_bf16x8(float4 a, float4 b) {
    uint4 o;
    o.x = ((__float_as_uint(a.x) + 0x8000u) >> 16) | ((__float_as_uint(a.y) + 0x8000u) & 0xFFFF0000u);
    o.y = ((__float_as_uint(a.z) + 0x8000u) >> 16) | ((__float_as_uint(a.w) + 0x8000u) & 0xFFFF0000u);
    o.z = ((__float_as_uint(b.x) + 0x8000u) >> 16) | ((__float_as_uint(b.y) + 0x8000u) & 0xFFFF0000u);
    o.w = ((__float_as_uint(b.z) + 0x8000u) >> 16) | ((__float_as_uint(b.w) + 0x8000u) & 0xFFFF0000u);
    return o;
}

// Swizzled LDS tiles: global 16B-chunk g of row r stored at LDS chunk
// g ^ (r & (nchunk-1)); DMA encodes the permutation on the source address.
// MFMA frag reads then spread a quad's 16 lanes across all banks (2-way max).

// ---------------------------------------------------------------------------
// prep_w: Wt[mat][n][k] (bf16) <- W[k][n] (fp32).  grid (16,3), block 256.
// ---------------------------------------------------------------------------
__global__ __launch_bounds__(256)
void prep_w_kernel(const float* __restrict__ Wq, const float* __restrict__ Wk,
                   const float* __restrict__ Wv, unsigned short* __restrict__ Wt)
{
    const int mat = blockIdx.y;
    const float* __restrict__ W = (mat == 0) ? Wq : (mat == 1) ? Wk : Wv;
    const int k0 = blockIdx.x * 64;
    __shared__ float T[64][65];
    const int t = threadIdx.x;
    #pragma unroll
    for (int i = 0; i < 16; ++i) {
        const int idx = t + i * 256;
        T[idx >> 6][idx & 63] = W[(size_t)(k0 + (idx >> 6)) * HD + (idx & 63)];
    }
    __syncthreads();
    const int n = t >> 2;
    const int c = t & 3;
    union { unsigned short h[16]; uint4 v[2]; } buf;
    #pragma unroll
    for (int j = 0; j < 16; ++j) buf.h[j] = f2bf(T[c * 16 + j][n]);
    unsigned short* dst = Wt + ((size_t)mat * HD + n) * DIM + k0 + c * 16;
    *(uint4*)dst       = buf.v[0];
    *(uint4*)(dst + 8) = buf.v[1];
}

// ---------------------------------------------------------------------------
// qkv_mfma v2: tile 32 rows x 192 cols, BK=64, DOUBLE-BUFFERED W + X tiles.
// The next tile's W DMA (24 KB via gld_lds) and x loads are issued at the TOP
// of the compute phase, so the barrier's vmcnt(0) drain overlaps MFMA + the
// HBM in-flight window instead of being fully exposed (the round-0 flaw).
// block 384 thr = 6 waves; wave w: rows (w&1)*16..+15, mat = w>>1 (4 acc).
// grid 512 = 2 blocks/CU (LDS 56 KB).  16 K-iterations.
// Q is pre-scaled by QSCALE.  Outputs: Q,K row-major bf16; V^T bf16.
// ---------------------------------------------------------------------------
__global__ __launch_bounds__(384)
void qkv_mfma_kernel(const float* __restrict__ x,
                     const unsigned short* __restrict__ Wt,
                     const float* __restrict__ bq, const float* __restrict__ bk,
                     const float* __restrict__ bv,
                     unsigned short* __restrict__ Qg,
                     unsigned short* __restrict__ Kg,
                     unsigned short* __restrict__ Vtg)
{
    __shared__ unsigned short Xs[2][32][64];    // 8 KB, swizzled chunks (key r&7)
    __shared__ unsigned short Ws[2][192][64];   // 48 KB, swizzled chunks

    const int t    = threadIdx.x;
    const int lane = t & 63;
    const int w    = t >> 6;         // 0..5
    const int col  = lane & 15;
    const int quad = lane >> 4;
    const int rh   = w & 1;          // 16-row half
    const int mat  = w >> 1;         // 0=Q, 1=K, 2=V
    const int row0 = blockIdx.x * 32;

    const int r8  = lane >> 3;       // row within an 8-row DMA call
    const int ch8 = lane & 7;        // 16B chunk within row (8 chunks)
    const int wswz = (ch8 ^ r8) * 8; // source swizzle (rbase ≡ 0 mod 8)

    f32x4 acc[4];
    #pragma unroll
    for (int i = 0; i < 4; ++i) acc[i] = (f32x4){0.f, 0.f, 0.f, 0.f};

    // x staging: threads 0..255, 8 floats each (32 rows x 64 cols fp32)
    const int xr  = t >> 3;          // row 0..31
    const int xc0 = t & 7;           // 8-float chunk 0..7
    const float* __restrict__ xrow = &x[(size_t)(row0 + xr) * DIM];

    // ---- prologue: stage tile 0 into buffer 0 ----
    #pragma unroll
    for (int ii = 0; ii < 4; ++ii) {
        const int rbase = w * 32 + ii * 8;
        gld_lds16(&Wt[(size_t)(rbase + r8) * DIM + wswz], &Ws[0][rbase][0]);
    }
    float4 xa, xb;
    if (t < 256) {
        xa = *(const float4*)(xrow + xc0 * 8);
        xb = *(const float4*)(xrow + xc0 * 8 + 4);
        *(uint4*)&Xs[0][xr][(xc0 ^ (xr & 7)) * 8] = pack_bf16x8(xa, xb);
    }
    __syncthreads();   // tile 0 ready (W DMA drained + X stores visible)

    int buf = 0;
    for (int it = 0; it < 16; ++it) {
        // issue next tile's staging FIRST so it overlaps this tile's MFMAs
        if (it < 15) {
            const int k0n = (it + 1) * 64;
            #pragma unroll
            for (int ii = 0; ii < 4; ++ii) {
                const int rbase = w * 32 + ii * 8;
                gld_lds16(&Wt[(size_t)(rbase + r8) * DIM + k0n + wswz],
                          &Ws[buf ^ 1][rbase][0]);
            }
            if (t < 256) {
                xa = *(const float4*)(xrow + k0n + xc0 * 8);
                xb = *(const float4*)(xrow + k0n + xc0 * 8 + 4);
            }
        }
        // compute on buf
        #pragma unroll
        for (int ks = 0; ks < 2; ++ks) {
            const int fswz = ((ks * 4 + quad) ^ (col & 7)) * 8;  // frag rows ≡ col (mod 8)
            const bf16x8 a = *(const bf16x8*)&Xs[buf][rh * 16 + col][fswz];
            #pragma unroll
            for (int nt = 0; nt < 4; ++nt) {
                const bf16x8 b = *(const bf16x8*)&Ws[buf][mat * 64 + nt * 16 + col][fswz];
                acc[nt] = __builtin_amdgcn_mfma_f32_16x16x32_bf16(a, b, acc[nt], 0, 0, 0);
            }
        }
        __syncthreads();   // readers of buf done; drains next-tile W DMA + x loads
        if (it < 15 && t < 256)
            *(uint4*)&Xs[buf ^ 1][xr][(xc0 ^ (xr & 7)) * 8] = pack_bf16x8(xa, xb);
        __syncthreads();   // next tile's X visible
        buf ^= 1;
    }

    // Epilogue.  C layout: col = lane&15, row = quad*4 + r.
    const int b    = row0 / SEQ;
    const int s0   = (row0 % SEQ) + rh * 16 + quad * 4;
    const int grow = row0 + rh * 16 + quad * 4;
    const float* __restrict__ bias = (mat == 0) ? bq : (mat == 1) ? bk : bv;
    const float oscale = (mat == 0) ? QSCALE : 1.0f;   // fold softmax scale into Q
    #pragma unroll
    for (int nt = 0; nt < 4; ++nt) {
        const int nn = nt * 16 + col;
        const float bvv = bias[nn];
        if (mat < 2) {
            unsigned short* __restrict__ o = (mat == 0) ? Qg : Kg;
            #pragma unroll
            for (int r = 0; r < 4; ++r)
                o[(size_t)(grow + r) * HD + nn] = f2bf((acc[nt][r] + bvv) * oscale);
        } else {
            const unsigned lo = (unsigned)f2bf(acc[nt][0] + bvv) | ((unsigned)f2bf(acc[nt][1] + bvv) << 16);
            const unsigned hi = (unsigned)f2bf(acc[nt][2] + bvv) | ((unsigned)f2bf(acc[nt][3] + bvv) << 16);
            *(uint2*)&Vtg[((size_t)b * HD + nn) * SEQ + s0] = make_uint2(lo, hi);
        }
    }
}

// ---------------------------------------------------------------------------
// attn_part: split-key flash attention, no online max (scores bounded),
// P = exp2(QK^T) with scale folded into Q.  Partials in bf16.
// grid (8, 144): x = batch (XCD-aligned: linear id ≡ batch mod 8, so each
// XCD's L2 caches one batch's K/V), y = compacted (c, qt) triangle.
// block 256 thr (4 waves x 16 q rows), <=4 K-iters.
// ---------------------------------------------------------------------------
__global__ __launch_bounds__(256)
void attn_part_kernel(const unsigned short* __restrict__ Qg,
                      const unsigned short* __restrict__ Kg,
                      const unsigned short* __restrict__ Vtg,
                      unsigned short* __restrict__ Opart,  // [2048][64][64] bf16
                      float* __restrict__ Lsum)            // [2048][64]
{
    const int b = blockIdx.x;
    // decode compacted triangle: for chunk c, valid qt in [4c, 31]
    int y = blockIdx.y, c = 0;
    while (y >= 32 - 4 * c) { y -= 32 - 4 * c; ++c; }
    const int qt = y + 4 * c;

    __shared__ unsigned short Ks[64][64];     // [key][d], swizzled (key r&7)
    __shared__ unsigned short Vs[64][64];     // [d][key], swizzled
    __shared__ unsigned short Ps[4][16][76];  // per-wave P, A layout [m][key]

    const int t    = threadIdx.x;
    const int w    = t >> 6;
    const int lane = t & 63;
    const int col  = lane & 15;
    const int quad = lane >> 4;
    const int q0w  = qt * QTILE + w * 16;
    const size_t gq = (size_t)b * SEQ + q0w;

    const bf16x8 aq0 = *(const bf16x8*)&Qg[(gq + col) * HD + quad * 8];
    const bf16x8 aq1 = *(const bf16x8*)&Qg[(gq + col) * HD + 32 + quad * 8];

    f32x4 oacc[4];
    #pragma unroll
    for (int n = 0; n < 4; ++n) oacc[n] = (f32x4){0.f, 0.f, 0.f, 0.f};
    float lpart[4] = {0.f, 0.f, 0.f, 0.f};   // per-lane partial denominators

    const int kbeg   = c * CHUNK;
    const int kend   = min((c + 1) * CHUNK, (qt + 1) * QTILE);
    const int ntiles = (kend - kbeg + 63) >> 6;

    const int r8 = lane >> 3, ch = lane & 7;
    const int swzr = (ch ^ r8) * 8;
    const unsigned short* kgb = Kg  + (size_t)b * SEQ * HD;
    const unsigned short* vgb = Vtg + (size_t)b * HD * SEQ;

    for (int it = 0; it < ntiles; ++it) {
        const int j0 = kbeg + it * 64;
        __syncthreads();
        // stage K (8 KB) + V^T (8 KB): 4 waves x 2 calls x 8 rows each
        #pragma unroll
        for (int ii = 0; ii < 2; ++ii) {
            const int rb = w * 16 + ii * 8;
            gld_lds16(&kgb[(size_t)(j0 + rb + r8) * HD + swzr], &Ks[rb][0]);
            gld_lds16(&vgb[(size_t)(rb + r8) * SEQ + j0 + swzr], &Vs[rb][0]);
        }
        __syncthreads();

        if (j0 <= q0w + 15) {   // wave-uniform: skip fully-masked tiles
            // scores (log2 domain: Q carries 0.125*log2e)
            f32x4 scv[4];
            #pragma unroll
            for (int nt = 0; nt < 4; ++nt) {
                const int sw0 = (quad ^ (col & 7)) * 8;
                const int sw1 = ((4 + quad) ^ (col & 7)) * 8;
                const bf16x8 bk0 = *(const bf16x8*)&Ks[nt * 16 + col][sw0];
                const bf16x8 bk1 = *(const bf16x8*)&Ks[nt * 16 + col][sw1];
                f32x4 s = __builtin_amdgcn_mfma_f32_16x16x32_bf16(aq0, bk0, (f32x4){0.f,0.f,0.f,0.f}, 0, 0, 0);
                s = __builtin_amdgcn_mfma_f32_16x16x32_bf16(aq1, bk1, s, 0, 0, 0);
                scv[nt] = s;
            }
            const bool needmask = (j0 + 63 > q0w);
            #pragma unroll
            for (int r = 0; r < 4; ++r) {
                const int row = q0w + quad * 4 + r;
                #pragma unroll
                for (int nt = 0; nt < 4; ++nt) {
                    float s = scv[nt][r];
                    if (needmask)
                        s = (j0 + nt * 16 + col <= row) ? s : -INFINITY;
                    const float p = fast_exp2(s);   // exp2(-inf) = 0 handles mask
                    lpart[r] += p;
                    Ps[w][quad * 4 + r][nt * 16 + col] = f2bf_hu(p);  // same-wave LDS
                }
            }
            // PV: O += P V
            #pragma unroll
            for (int ks = 0; ks < 2; ++ks) {
                const bf16x8 ap = *(const bf16x8*)&Ps[w][col][ks * 32 + quad * 8];
                const int fswz = ((ks * 4 + quad) ^ (col & 7)) * 8;
                #pragma unroll
                for (int n = 0; n < 4; ++n) {
                    const bf16x8 bv2 = *(const bf16x8*)&Vs[n * 16 + col][fswz];
                    oacc[n] = __builtin_amdgcn_mfma_f32_16x16x32_bf16(ap, bv2, oacc[n], 0, 0, 0);
                }
            }
        }
    }

    // deferred 16-lane reduction of the denominators (once per kernel)
    #pragma unroll
    for (int r = 0; r < 4; ++r) {
        #pragma unroll
        for (int off = 1; off < 16; off <<= 1)
            lpart[r] += __shfl_xor(lpart[r], off, 64);
    }

    // epilogue: un-normalized bf16 partials + fp32 denominators
    const int blk = (b * NQT + qt) * NCHUNK + c;
    unsigned short* Ob = Opart + (size_t)blk * (QTILE * HD);
    #pragma unroll
    for (int n = 0; n < 4; ++n)
        #pragma unroll
        for (int r = 0; r < 4; ++r)
            Ob[(w * 16 + quad * 4 + r) * HD + n * 16 + col] = f2bf(oacc[n][r]);
    if (col == 0) {
        float* lb = Lsum + (size_t)blk * QTILE;
        #pragma unroll
        for (int r = 0; r < 4; ++r)
            lb[w * 16 + quad * 4 + r] = lpart[r];
    }
}

// ---------------------------------------------------------------------------
// combine: out = sum(Opart) / sum(l).  1 thread per (row, 4 dims): uint2
// bf16 loads, float4 store.  grid 1024 x 256.
// ---------------------------------------------------------------------------
__global__ __launch_bounds__(256)
void combine_kernel(const unsigned short* __restrict__ Opart,
                    const float* __restrict__ Lsum,
                    float* __restrict__ out)
{
    const int gid = blockIdx.x * 256 + threadIdx.x;
    const int i   = gid >> 4;          // global row
    const int d4  = (gid & 15) * 4;    // dim group
    const int b   = i >> 11;
    const int s   = i & 2047;
    const int qt  = s >> 6;            // 64-row q tile
    const int r64 = s & 63;
    const int nc  = (s >> 8) + 1;      // chunks touching this row
    const int blk0 = (b * NQT + qt) * NCHUNK;

    float L = 0.f;
    float a0 = 0.f, a1 = 0.f, a2 = 0.f, a3 = 0.f;
    for (int cc = 0; cc < nc; ++cc) {
        L += Lsum[(size_t)(blk0 + cc) * QTILE + r64];
        const uint2 u = *(const uint2*)(Opart + (size_t)(blk0 + cc) * (QTILE * HD) + r64 * HD + d4);
        a0 += __uint_as_float(u.x << 16);
        a1 += __uint_as_float(u.x & 0xFFFF0000u);
        a2 += __uint_as_float(u.y << 16);
        a3 += __uint_as_float(u.y & 0xFFFF0000u);
    }
    const float rL = 1.0f / L;
    float4 o; o.x = a0 * rL; o.y = a1 * rL; o.z = a2 * rL; o.w = a3 * rL;
    *(float4*)&out[(size_t)i * HD + d4] = o;
}

// ---------------------------------------------------------------------------
extern "C" void kernel_launch(void* const* d_in, const int* in_sizes, int n_in,
                              void* d_out, int out_size, void* d_ws, size_t ws_size,
                              hipStream_t stream) {
    const float* x  = (const float*)d_in[0];
    const float* Wq = (const float*)d_in[1];
    const float* bq = (const float*)d_in[2];
    const float* Wk = (const float*)d_in[3];
    const float* bk = (const float*)d_in[4];
    const float* Wv = (const float*)d_in[5];
    const float* bv = (const float*)d_in[6];
    float* out = (float*)d_out;

    unsigned short* Wt    = (unsigned short*)d_ws;        // [3][64][1024] bf16
    unsigned short* Qg    = Wt + (size_t)3 * HD * DIM;    // [16384][64] bf16 (pre-scaled)
    unsigned short* Kg    = Qg + (size_t)NROWS * HD;      // [16384][64] bf16
    unsigned short* Vtg   = Kg + (size_t)NROWS * HD;      // [8][64][2048] bf16
    unsigned short* Opart = Vtg + (size_t)BATCH * HD * SEQ;               // [2048][64][64] bf16
    float* Lsum = (float*)(Opart + (size_t)BATCH * NQT * NCHUNK * QTILE * HD);  // [2048][64]

    prep_w_kernel<<<dim3(16, 3), 256, 0, stream>>>(Wq, Wk, Wv, Wt);
    qkv_mfma_kernel<<<dim3(NROWS / 32), 384, 0, stream>>>(x, Wt, bq, bk, bv, Qg, Kg, Vtg);
    attn_part_kernel<<<dim3(8, 144), 256, 0, stream>>>(Qg, Kg, Vtg, Opart, Lsum);
    combine_kernel<<<dim3(NROWS * 16 / 256), 256, 0, stream>>>(Opart, Lsum, out);
}

// Round 3
// 151.289 us; speedup vs baseline: 1.6559x; 1.0007x over previous
//
#include <hip/hip_runtime.h>
#include <math.h>

#define BATCH 8
#define SEQ   2048
#define DIM   1024
#define HD    64
#define NROWS (BATCH * SEQ)   // 16384
#define CHUNK 256
#define NCHUNK 8              // SEQ / CHUNK
#define QTILE 64              // q rows per attention block
#define NQT   (SEQ / QTILE)   // 32
#define QSCALE 0.1803368801f  // 0.125 * log2(e): folded into Q so P = exp2(QK^T)

typedef __attribute__((ext_vector_type(8))) short bf16x8;  // 8 bf16 = 4 VGPRs
typedef __attribute__((ext_vector_type(4))) float f32x4;

__device__ __forceinline__ unsigned short f2bf(float f) {
    unsigned u = __float_as_uint(f);
    u = (u + 0x7FFFu + ((u >> 16) & 1u)) >> 16;   // RNE
    return (unsigned short)u;
}
// cheap half-up rounding (2 ops)
__device__ __forceinline__ unsigned short f2bf_hu(float f) {
    return (unsigned short)((__float_as_uint(f) + 0x8000u) >> 16);
}
__device__ __forceinline__ float fast_exp2(float x) {
#if __has_builtin(__builtin_amdgcn_exp2f)
    return __builtin_amdgcn_exp2f(x);
#else
    return exp2f(x);
#endif
}

// async global -> LDS DMA, 16 B per lane.  LDS dest = wave-uniform base + lane*16.
__device__ __forceinline__ void gld_lds16(const void* g, void* l) {
    __builtin_amdgcn_global_load_lds(
        (const __attribute__((address_space(1))) void*)g,
        (__attribute__((address_space(3))) void*)l, 16, 0, 0);
}

// pack 8 fp32 -> 8 bf16 (half-up) as one uint4
__device__ __forceinline__ uint4 pack_bf16x8(float4 a, float4 b) {
    uint4 o;
    o.x = ((__float_as_uint(a.x) + 0x8000u) >> 16) | ((__float_as_uint(a.y) + 0x8000u) & 0xFFFF0000u);
    o.y = ((__float_as_uint(a.z) + 0x8000u) >> 16) | ((__float_as_uint(a.w) + 0x8000u) & 0xFFFF0000u);
    o.z = ((__float_as_uint(b.x) + 0x8000u) >> 16) | ((__float_as_uint(b.y) + 0x8000u) & 0xFFFF0000u);
    o.w = ((__float_as_uint(b.z) + 0x8000u) >> 16) | ((__float_as_uint(b.w) + 0x8000u) & 0xFFFF0000u);
    return o;
}

#define CFENCE() asm volatile("" ::: "memory")
#define RAW_BAR() do { CFENCE(); __builtin_amdgcn_s_barrier(); CFENCE(); } while (0)

// ---------------------------------------------------------------------------
// prep_w: Wt[mat][n][k] (bf16) <- W[k][n] (fp32).  grid (16,3), block 256.
// ---------------------------------------------------------------------------
__global__ __launch_bounds__(256)
void prep_w_kernel(const float* __restrict__ Wq, const float* __restrict__ Wk,
                   const float* __restrict__ Wv, unsigned short* __restrict__ Wt)
{
    const int mat = blockIdx.y;
    const float* __restrict__ W = (mat == 0) ? Wq : (mat == 1) ? Wk : Wv;
    const int k0 = blockIdx.x * 64;
    __shared__ float T[64][65];
    const int t = threadIdx.x;
    #pragma unroll
    for (int i = 0; i < 16; ++i) {
        const int idx = t + i * 256;
        T[idx >> 6][idx & 63] = W[(size_t)(k0 + (idx >> 6)) * HD + (idx & 63)];
    }
    __syncthreads();
    const int n = t >> 2;
    const int c = t & 3;
    union { unsigned short h[16]; uint4 v[2]; } buf;
    #pragma unroll
    for (int j = 0; j < 16; ++j) buf.h[j] = f2bf(T[c * 16 + j][n]);
    unsigned short* dst = Wt + ((size_t)mat * HD + n) * DIM + k0 + c * 16;
    *(uint4*)dst       = buf.v[0];
    *(uint4*)(dst + 8) = buf.v[1];
}

// ---------------------------------------------------------------------------
// qkv_mfma v3: tile 32 rows x 192 cols, BK=64, double-buffered, with
// RAW s_barrier + per-wave COUNTED s_waitcnt vmcnt(N) (T4): the just-issued
// stage(i+1) DMAs stay in flight across the barrier; we only wait for
// stage(i), which has had a full iteration to complete.  All staging (W bf16
// and X fp32) goes through global_load_lds so vmcnt counting is exact;
// fp32->bf16 conversion happens at the A-fragment read (16 VALU/wave/iter).
// block 384 thr = 6 waves; wave w: rows (w&1)*16..+15, mat = w>>1 (4 acc).
// grid 512 = 2 blocks/CU (LDS 64 KB).  16 K-iterations.
// Per-wave DMA counts/iter: waves 0-3: 4 W + 2 X = 6; waves 4-5: 4 W.
// ---------------------------------------------------------------------------
__global__ __launch_bounds__(384)
void qkv_mfma_kernel(const float* __restrict__ x,
                     const unsigned short* __restrict__ Wt,
                     const float* __restrict__ bq, const float* __restrict__ bk,
                     const float* __restrict__ bv,
                     unsigned short* __restrict__ Qg,
                     unsigned short* __restrict__ Kg,
                     unsigned short* __restrict__ Vtg)
{
    __shared__ float          Xs[2][32][64];    // 16 KB fp32, src-swizzled chunks (key r&15)
    __shared__ unsigned short Ws[2][192][64];   // 48 KB bf16, src-swizzled chunks (key r&7)

    const int t    = threadIdx.x;
    const int lane = t & 63;
    const int w    = t >> 6;         // 0..5
    const int col  = lane & 15;
    const int quad = lane >> 4;
    const int rh   = w & 1;          // 16-row half
    const int mat  = w >> 1;         // 0=Q, 1=K, 2=V
    const int row0 = blockIdx.x * 32;

    const int r8  = lane >> 3;       // W: row within an 8-row DMA call
    const int ch8 = lane & 7;        // W: 16B chunk within row (8 chunks)
    const int wswz = (ch8 ^ r8) * 8; // W source swizzle (rbase ≡ 0 mod 8)

    const int xr4 = lane >> 4;       // X: row within a 4-row DMA call
    const int xch = lane & 15;       // X: 16B chunk (4 floats) within row

    f32x4 acc[4];
    #pragma unroll
    for (int i = 0; i < 4; ++i) acc[i] = (f32x4){0.f, 0.f, 0.f, 0.f};

    auto stageW = [&](int it, int bb) {
        const int k0 = it * 64;
        #pragma unroll
        for (int ii = 0; ii < 4; ++ii) {
            const int rbase = w * 32 + ii * 8;
            gld_lds16(&Wt[(size_t)(rbase + r8) * DIM + k0 + wswz], &Ws[bb][rbase][0]);
        }
    };
    auto stageX = [&](int it, int bb) {   // waves 0..3 only: 2 calls x 4 rows
        const int k0 = it * 64;
        #pragma unroll
        for (int ii = 0; ii < 2; ++ii) {
            const int rl = w * 8 + ii * 4;     // local row base
            const int rr = rl + xr4;           // + lane row
            gld_lds16(&x[(size_t)(row0 + rr) * DIM + k0 + ((xch ^ (rr & 15)) << 2)],
                      &Xs[bb][rl][0]);
        }
    };
    auto compute = [&](int bb) {
        #pragma unroll
        for (int ks = 0; ks < 2; ++ks) {
            const int c0 = ks * 8 + quad * 2;
            const float* xsr = &Xs[bb][rh * 16 + col][0];
            const float4 u0 = *(const float4*)(xsr + ((c0 ^ col) << 2));
            const float4 u1 = *(const float4*)(xsr + (((c0 + 1) ^ col) << 2));
            union { uint4 u; bf16x8 h; } av;
            av.u = pack_bf16x8(u0, u1);
            const int fswz = ((ks * 4 + quad) ^ (col & 7)) * 8;
            #pragma unroll
            for (int nt = 0; nt < 4; ++nt) {
                const bf16x8 b = *(const bf16x8*)&Ws[bb][mat * 64 + nt * 16 + col][fswz];
                acc[nt] = __builtin_amdgcn_mfma_f32_16x16x32_bf16(av.h, b, acc[nt], 0, 0, 0);
            }
        }
    };

    // prologue: issue stage(0) into buf 0 (completion enforced at it=0's wait)
    stageW(0, 0);
    if (w < 4) stageX(0, 0);

    int buf = 0;
    for (int it = 0; it < 16; ++it) {
        RAW_BAR();                    // [A] all waves done reading buf^1 (prev compute)
        if (it < 15) {
            stageW(it + 1, buf ^ 1);  // [B] prefetch next tile (stays in flight)
            if (w < 4) {
                stageX(it + 1, buf ^ 1);
                asm volatile("s_waitcnt vmcnt(6)" ::: "memory");  // [C] stage(it) landed
            } else {
                asm volatile("s_waitcnt vmcnt(4)" ::: "memory");
            }
        } else {
            asm volatile("s_waitcnt vmcnt(0)" ::: "memory");      // drain last stage
        }
        RAW_BAR();                    // [D] every wave's stage(it) landed
        compute(buf);                 // ds_read + 8 MFMA on tile it
        buf ^= 1;
    }

    // Epilogue.  C layout: col = lane&15, row = quad*4 + r.
    const int b    = row0 / SEQ;
    const int s0   = (row0 % SEQ) + rh * 16 + quad * 4;
    const int grow = row0 + rh * 16 + quad * 4;
    const float* __restrict__ bias = (mat == 0) ? bq : (mat == 1) ? bk : bv;
    const float oscale = (mat == 0) ? QSCALE : 1.0f;   // fold softmax scale into Q
    #pragma unroll
    for (int nt = 0; nt < 4; ++nt) {
        const int nn = nt * 16 + col;
        const float bvv = bias[nn];
        if (mat < 2) {
            unsigned short* __restrict__ o = (mat == 0) ? Qg : Kg;
            #pragma unroll
            for (int r = 0; r < 4; ++r)
                o[(size_t)(grow + r) * HD + nn] = f2bf((acc[nt][r] + bvv) * oscale);
        } else {
            const unsigned lo = (unsigned)f2bf(acc[nt][0] + bvv) | ((unsigned)f2bf(acc[nt][1] + bvv) << 16);
            const unsigned hi = (unsigned)f2bf(acc[nt][2] + bvv) | ((unsigned)f2bf(acc[nt][3] + bvv) << 16);
            *(uint2*)&Vtg[((size_t)b * HD + nn) * SEQ + s0] = make_uint2(lo, hi);
        }
    }
}

// ---------------------------------------------------------------------------
// attn_part: split-key flash attention, no online max (scores bounded),
// P = exp2(QK^T) with scale folded into Q.  Partials in bf16.
// grid (8, 144): x = batch (XCD-aligned: linear id ≡ batch mod 8, so each
// XCD's L2 caches one batch's K/V), y = compacted (c, qt) triangle.
// block 256 thr (4 waves x 16 q rows), <=4 K-iters.
// ---------------------------------------------------------------------------
__global__ __launch_bounds__(256)
void attn_part_kernel(const unsigned short* __restrict__ Qg,
                      const unsigned short* __restrict__ Kg,
                      const unsigned short* __restrict__ Vtg,
                      unsigned short* __restrict__ Opart,  // [2048][64][64] bf16
                      float* __restrict__ Lsum)            // [2048][64]
{
    const int b = blockIdx.x;
    // decode compacted triangle: for chunk c, valid qt in [4c, 31]
    int y = blockIdx.y, c = 0;
    while (y >= 32 - 4 * c) { y -= 32 - 4 * c; ++c; }
    const int qt = y + 4 * c;

    __shared__ unsigned short Ks[64][64];     // [key][d], swizzled (key r&7)
    __shared__ unsigned short Vs[64][64];     // [d][key], swizzled
    __shared__ unsigned short Ps[4][16][76];  // per-wave P, A layout [m][key]

    const int t    = threadIdx.x;
    const int w    = t >> 6;
    const int lane = t & 63;
    const int col  = lane & 15;
    const int quad = lane >> 4;
    const int q0w  = qt * QTILE + w * 16;
    const size_t gq = (size_t)b * SEQ + q0w;

    const bf16x8 aq0 = *(const bf16x8*)&Qg[(gq + col) * HD + quad * 8];
    const bf16x8 aq1 = *(const bf16x8*)&Qg[(gq + col) * HD + 32 + quad * 8];

    f32x4 oacc[4];
    #pragma unroll
    for (int n = 0; n < 4; ++n) oacc[n] = (f32x4){0.f, 0.f, 0.f, 0.f};
    float lpart[4] = {0.f, 0.f, 0.f, 0.f};   // per-lane partial denominators

    const int kbeg   = c * CHUNK;
    const int kend   = min((c + 1) * CHUNK, (qt + 1) * QTILE);
    const int ntiles = (kend - kbeg + 63) >> 6;

    const int r8 = lane >> 3, ch = lane & 7;
    const int swzr = (ch ^ r8) * 8;
    const unsigned short* kgb = Kg  + (size_t)b * SEQ * HD;
    const unsigned short* vgb = Vtg + (size_t)b * HD * SEQ;

    for (int it = 0; it < ntiles; ++it) {
        const int j0 = kbeg + it * 64;
        __syncthreads();
        // stage K (8 KB) + V^T (8 KB): 4 waves x 2 calls x 8 rows each
        #pragma unroll
        for (int ii = 0; ii < 2; ++ii) {
            const int rb = w * 16 + ii * 8;
            gld_lds16(&kgb[(size_t)(j0 + rb + r8) * HD + swzr], &Ks[rb][0]);
            gld_lds16(&vgb[(size_t)(rb + r8) * SEQ + j0 + swzr], &Vs[rb][0]);
        }
        __syncthreads();

        if (j0 <= q0w + 15) {   // wave-uniform: skip fully-masked tiles
            // scores (log2 domain: Q carries 0.125*log2e)
            f32x4 scv[4];
            #pragma unroll
            for (int nt = 0; nt < 4; ++nt) {
                const int sw0 = (quad ^ (col & 7)) * 8;
                const int sw1 = ((4 + quad) ^ (col & 7)) * 8;
                const bf16x8 bk0 = *(const bf16x8*)&Ks[nt * 16 + col][sw0];
                const bf16x8 bk1 = *(const bf16x8*)&Ks[nt * 16 + col][sw1];
                f32x4 s = __builtin_amdgcn_mfma_f32_16x16x32_bf16(aq0, bk0, (f32x4){0.f,0.f,0.f,0.f}, 0, 0, 0);
                s = __builtin_amdgcn_mfma_f32_16x16x32_bf16(aq1, bk1, s, 0, 0, 0);
                scv[nt] = s;
            }
            const bool needmask = (j0 + 63 > q0w);
            #pragma unroll
            for (int r = 0; r < 4; ++r) {
                const int row = q0w + quad * 4 + r;
                #pragma unroll
                for (int nt = 0; nt < 4; ++nt) {
                    float s = scv[nt][r];
                    if (needmask)
                        s = (j0 + nt * 16 + col <= row) ? s : -INFINITY;
                    const float p = fast_exp2(s);   // exp2(-inf) = 0 handles mask
                    lpart[r] += p;
                    Ps[w][quad * 4 + r][nt * 16 + col] = f2bf_hu(p);  // same-wave LDS
                }
            }
            // PV: O += P V
            #pragma unroll
            for (int ks = 0; ks < 2; ++ks) {
                const bf16x8 ap = *(const bf16x8*)&Ps[w][col][ks * 32 + quad * 8];
                const int fswz = ((ks * 4 + quad) ^ (col & 7)) * 8;
                #pragma unroll
                for (int n = 0; n < 4; ++n) {
                    const bf16x8 bv2 = *(const bf16x8*)&Vs[n * 16 + col][fswz];
                    oacc[n] = __builtin_amdgcn_mfma_f32_16x16x32_bf16(ap, bv2, oacc[n], 0, 0, 0);
                }
            }
        }
    }

    // deferred 16-lane reduction of the denominators (once per kernel)
    #pragma unroll
    for (int r = 0; r < 4; ++r) {
        #pragma unroll
        for (int off = 1; off < 16; off <<= 1)
            lpart[r] += __shfl_xor(lpart[r], off, 64);
    }

    // epilogue: un-normalized bf16 partials + fp32 denominators
    const int blk = (b * NQT + qt) * NCHUNK + c;
    unsigned short* Ob = Opart + (size_t)blk * (QTILE * HD);
    #pragma unroll
    for (int n = 0; n < 4; ++n)
        #pragma unroll
        for (int r = 0; r < 4; ++r)
            Ob[(w * 16 + quad * 4 + r) * HD + n * 16 + col] = f2bf(oacc[n][r]);
    if (col == 0) {
        float* lb = Lsum + (size_t)blk * QTILE;
        #pragma unroll
        for (int r = 0; r < 4; ++r)
            lb[w * 16 + quad * 4 + r] = lpart[r];
    }
}

// ---------------------------------------------------------------------------
// combine: out = sum(Opart) / sum(l).  1 thread per (row, 4 dims): uint2
// bf16 loads, float4 store.  grid 1024 x 256.
// ---------------------------------------------------------------------------
__global__ __launch_bounds__(256)
void combine_kernel(const unsigned short* __restrict__ Opart,
                    const float* __restrict__ Lsum,
                    float* __restrict__ out)
{
    const int gid = blockIdx.x * 256 + threadIdx.x;
    const int i   = gid >> 4;          // global row
    const int d4  = (gid & 15) * 4;    // dim group
    const int b   = i >> 11;
    const int s   = i & 2047;
    const int qt  = s >> 6;            // 64-row q tile
    const int r64 = s & 63;
    const int nc  = (s >> 8) + 1;      // chunks touching this row
    const int blk0 = (b * NQT + qt) * NCHUNK;

    float L = 0.f;
    float a0 = 0.f, a1 = 0.f, a2 = 0.f, a3 = 0.f;
    for (int cc = 0; cc < nc; ++cc) {
        L += Lsum[(size_t)(blk0 + cc) * QTILE + r64];
        const uint2 u = *(const uint2*)(Opart + (size_t)(blk0 + cc) * (QTILE * HD) + r64 * HD + d4);
        a0 += __uint_as_float(u.x << 16);
        a1 += __uint_as_float(u.x & 0xFFFF0000u);
        a2 += __uint_as_float(u.y << 16);
        a3 += __uint_as_float(u.y & 0xFFFF0000u);
    }
    const float rL = 1.0f / L;
    float4 o; o.x = a0 * rL; o.y = a1 * rL; o.z = a2 * rL; o.w = a3 * rL;
    *(float4*)&out[(size_t)i * HD + d4] = o;
}

// ---------------------------------------------------------------------------
extern "C" void kernel_launch(void* const* d_in, const int* in_sizes, int n_in,
                              void* d_out, int out_size, void* d_ws, size_t ws_size,
                              hipStream_t stream) {
    const float* x  = (const float*)d_in[0];
    const float* Wq = (const float*)d_in[1];
    const float* bq = (const float*)d_in[2];
    const float* Wk = (const float*)d_in[3];
    const float* bk = (const float*)d_in[4];
    const float* Wv = (const float*)d_in[5];
    const float* bv = (const float*)d_in[6];
    float* out = (float*)d_out;

    unsigned short* Wt    = (unsigned short*)d_ws;        // [3][64][1024] bf16
    unsigned short* Qg    = Wt + (size_t)3 * HD * DIM;    // [16384][64] bf16 (pre-scaled)
    unsigned short* Kg    = Qg + (size_t)NROWS * HD;      // [16384][64] bf16
    unsigned short* Vtg   = Kg + (size_t)NROWS * HD;      // [8][64][2048] bf16
    unsigned short* Opart = Vtg + (size_t)BATCH * HD * SEQ;               // [2048][64][64] bf16
    float* Lsum = (float*)(Opart + (size_t)BATCH * NQT * NCHUNK * QTILE * HD);  // [2048][64]

    prep_w_kernel<<<dim3(16, 3), 256, 0, stream>>>(Wq, Wk, Wv, Wt);
    qkv_mfma_kernel<<<dim3(NROWS / 32), 384, 0, stream>>>(x, Wt, bq, bk, bv, Qg, Kg, Vtg);
    attn_part_kernel<<<dim3(8, 144), 256, 0, stream>>>(Qg, Kg, Vtg, Opart, Lsum);
    combine_kernel<<<dim3(NROWS * 16 / 256), 256, 0, stream>>>(Opart, Lsum, out);
}

// Round 4
// 138.898 us; speedup vs baseline: 1.8036x; 1.0892x over previous
//
#include <hip/hip_runtime.h>
#include <math.h>

#define BATCH 8
#define SEQ   2048
#define DIM   1024
#define HD    64
#define NROWS (BATCH * SEQ)   // 16384
#define CHUNK 256
#define NCHUNK 8              // SEQ / CHUNK
#define QTILE 64              // q rows per attention block
#define NQT   (SEQ / QTILE)   // 32
#define QSCALE 0.1803368801f  // 0.125 * log2(e): folded into Q so P = exp2(QK^T)

typedef __attribute__((ext_vector_type(8))) short bf16x8;  // 8 bf16 = 4 VGPRs
typedef __attribute__((ext_vector_type(4))) float f32x4;

__device__ __forceinline__ unsigned short f2bf(float f) {
    unsigned u = __float_as_uint(f);
    u = (u + 0x7FFFu + ((u >> 16) & 1u)) >> 16;   // RNE
    return (unsigned short)u;
}
// cheap half-up rounding (2 ops)
__device__ __forceinline__ unsigned short f2bf_hu(float f) {
    return (unsigned short)((__float_as_uint(f) + 0x8000u) >> 16);
}
__device__ __forceinline__ float fast_exp2(float x) {
#if __has_builtin(__builtin_amdgcn_exp2f)
    return __builtin_amdgcn_exp2f(x);
#else
    return exp2f(x);
#endif
}

// async global -> LDS DMA, 16 B per lane.  LDS dest = wave-uniform base + lane*16.
__device__ __forceinline__ void gld_lds16(const void* g, void* l) {
    __builtin_amdgcn_global_load_lds(
        (const __attribute__((address_space(1))) void*)g,
        (__attribute__((address_space(3))) void*)l, 16, 0, 0);
}

// pack 8 fp32 -> 8 bf16 (half-up) as one uint4
__device__ __forceinline__ uint4 pack_bf16x8(float4 a, float4 b) {
    uint4 o;
    o.x = ((__float_as_uint(a.x) + 0x8000u) >> 16) | ((__float_as_uint(a.y) + 0x8000u) & 0xFFFF0000u);
    o.y = ((__float_as_uint(a.z) + 0x8000u) >> 16) | ((__float_as_uint(a.w) + 0x8000u) & 0xFFFF0000u);
    o.z = ((__float_as_uint(b.x) + 0x8000u) >> 16) | ((__float_as_uint(b.y) + 0x8000u) & 0xFFFF0000u);
    o.w = ((__float_as_uint(b.z) + 0x8000u) >> 16) | ((__float_as_uint(b.w) + 0x8000u) & 0xFFFF0000u);
    return o;
}

#define CFENCE() asm volatile("" ::: "memory")
#define RAW_BAR() do { CFENCE(); __builtin_amdgcn_s_barrier(); CFENCE(); } while (0)

// ---------------------------------------------------------------------------
// prep_w: Wt[mat][n][k] (bf16) <- W[k][n] (fp32).  grid (16,3), block 256.
// ---------------------------------------------------------------------------
__global__ __launch_bounds__(256)
void prep_w_kernel(const float* __restrict__ Wq, const float* __restrict__ Wk,
                   const float* __restrict__ Wv, unsigned short* __restrict__ Wt)
{
    const int mat = blockIdx.y;
    const float* __restrict__ W = (mat == 0) ? Wq : (mat == 1) ? Wk : Wv;
    const int k0 = blockIdx.x * 64;
    __shared__ float T[64][65];
    const int t = threadIdx.x;
    #pragma unroll
    for (int i = 0; i < 16; ++i) {
        const int idx = t + i * 256;
        T[idx >> 6][idx & 63] = W[(size_t)(k0 + (idx >> 6)) * HD + (idx & 63)];
    }
    __syncthreads();
    const int n = t >> 2;
    const int c = t & 3;
    union { unsigned short h[16]; uint4 v[2]; } buf;
    #pragma unroll
    for (int j = 0; j < 16; ++j) buf.h[j] = f2bf(T[c * 16 + j][n]);
    unsigned short* dst = Wt + ((size_t)mat * HD + n) * DIM + k0 + c * 16;
    *(uint4*)dst       = buf.v[0];
    *(uint4*)(dst + 8) = buf.v[1];
}

// ---------------------------------------------------------------------------
// qkv_mfma v4: tile 64 rows x 192 cols (grid 256 -> W re-stage traffic halved:
// all variants so far sit at the ~6.3 TB/s aggregate VMEM ceiling, dominated
// by 512 blocks each re-staging the full 393 KB W; fewer/bigger blocks cut
// total staged bytes 268 MB -> 167 MB).  BK=64, double-buffered LDS (64 KB),
// raw s_barrier + counted vmcnt(2) (stage(i+1) W stays in flight across the
// barrier; X is VGPR-prefetched 2 iterations deep and stored as bf16).
// 12 waves (768 thr): wave w -> mat = w>>2 (0=Q,1=K,2=V), row quarter wr = w&3.
// Per-wave per-iter VMEM: waves 0-7: 2 W-DMA + 2 X-loads; waves 8-11: 2 W-DMA.
// ---------------------------------------------------------------------------
__global__ __launch_bounds__(768)
void qkv_mfma_kernel(const float* __restrict__ x,
                     const unsigned short* __restrict__ Wt,
                     const float* __restrict__ bq, const float* __restrict__ bk,
                     const float* __restrict__ bv,
                     unsigned short* __restrict__ Qg,
                     unsigned short* __restrict__ Kg,
                     unsigned short* __restrict__ Vtg)
{
    __shared__ unsigned short Xs[2][64][64];    // 16 KB bf16, swizzled chunks (key r&7)
    __shared__ unsigned short Ws[2][192][64];   // 48 KB bf16, swizzled chunks (key r&7)

    const int t    = threadIdx.x;
    const int lane = t & 63;
    const int w    = t >> 6;         // 0..11
    const int col  = lane & 15;
    const int quad = lane >> 4;
    const int mat  = w >> 2;         // 0=Q, 1=K, 2=V
    const int wr   = w & 3;          // 16-row quarter
    const int row0 = blockIdx.x * 64;

    const int r8  = lane >> 3;       // W: row within an 8-row DMA call
    const int ch8 = lane & 7;        // W: 16B chunk within row (8 chunks)
    const int wswz = (ch8 ^ r8) * 8; // W source swizzle (rbase ≡ 0 mod 8)

    f32x4 acc[4];
    #pragma unroll
    for (int i = 0; i < 4; ++i) acc[i] = (f32x4){0.f, 0.f, 0.f, 0.f};

    // X staging: threads 0..511 own (row xr, 8-float chunk xc0)
    const int xr  = t >> 3;          // 0..63
    const int xc0 = t & 7;           // 0..7
    const float* __restrict__ xrow = &x[(size_t)(row0 + xr) * DIM];

    auto stageW = [&](int it, int bb) {   // 2 calls x 8 rows = 16 rows per wave
        const int k0 = it * 64;
        #pragma unroll
        for (int ii = 0; ii < 2; ++ii) {
            const int rbase = w * 16 + ii * 8;
            gld_lds16(&Wt[(size_t)(rbase + r8) * DIM + k0 + wswz], &Ws[bb][rbase][0]);
        }
    };
    auto computeT = [&](int bb) {
        #pragma unroll
        for (int ks = 0; ks < 2; ++ks) {
            const int fswz = ((ks * 4 + quad) ^ (col & 7)) * 8;
            const bf16x8 a = *(const bf16x8*)&Xs[bb][wr * 16 + col][fswz];
            #pragma unroll
            for (int nt = 0; nt < 4; ++nt) {
                const bf16x8 b = *(const bf16x8*)&Ws[bb][mat * 64 + nt * 16 + col][fswz];
                acc[nt] = __builtin_amdgcn_mfma_f32_16x16x32_bf16(a, b, acc[nt], 0, 0, 0);
            }
        }
    };

    // ---- prologue: stage tile 0; prefetch X(1) into regs ----
    float4 xa, xb;
    stageW(0, 0);
    if (t < 512) {
        xa = *(const float4*)(xrow + xc0 * 8);
        xb = *(const float4*)(xrow + xc0 * 8 + 4);
    }
    asm volatile("s_waitcnt vmcnt(0)" ::: "memory");
    if (t < 512) {
        *(uint4*)&Xs[0][xr][(xc0 ^ (xr & 7)) * 8] = pack_bf16x8(xa, xb);
        xa = *(const float4*)(xrow + 64 + xc0 * 8);
        xb = *(const float4*)(xrow + 64 + xc0 * 8 + 4);
    }

    int buf = 0;
    for (int it = 0; it < 16; ++it) {
        RAW_BAR();                    // [A] all waves done reading buf^1
        if (it < 15) {
            stageW(it + 1, buf ^ 1);  // prefetch next W tile (stays in flight)
            // drains W(it) + X-loads(it+1); leaves W(it+1) in flight
            asm volatile("s_waitcnt vmcnt(2)" ::: "memory");
            if (t < 512) {
                *(uint4*)&Xs[buf ^ 1][xr][(xc0 ^ (xr & 7)) * 8] = pack_bf16x8(xa, xb);
                if (it < 14) {
                    const float* xp = xrow + (it + 2) * 64;
                    xa = *(const float4*)(xp + xc0 * 8);
                    xb = *(const float4*)(xp + xc0 * 8 + 4);
                }
            }
        } else {
            asm volatile("s_waitcnt vmcnt(0)" ::: "memory");   // drain last W
        }
        RAW_BAR();                    // [D] tile `it` fully in LDS
        computeT(buf);                // ds_read + 8 MFMA per wave
        buf ^= 1;
    }

    // Epilogue.  C layout: col = lane&15, row = quad*4 + r.
    const int b    = row0 / SEQ;
    const int s0   = (row0 % SEQ) + wr * 16 + quad * 4;
    const int grow = row0 + wr * 16 + quad * 4;
    const float* __restrict__ bias = (mat == 0) ? bq : (mat == 1) ? bk : bv;
    const float oscale = (mat == 0) ? QSCALE : 1.0f;   // fold softmax scale into Q
    #pragma unroll
    for (int nt = 0; nt < 4; ++nt) {
        const int nn = nt * 16 + col;
        const float bvv = bias[nn];
        if (mat < 2) {
            unsigned short* __restrict__ o = (mat == 0) ? Qg : Kg;
            #pragma unroll
            for (int r = 0; r < 4; ++r)
                o[(size_t)(grow + r) * HD + nn] = f2bf((acc[nt][r] + bvv) * oscale);
        } else {
            const unsigned lo = (unsigned)f2bf(acc[nt][0] + bvv) | ((unsigned)f2bf(acc[nt][1] + bvv) << 16);
            const unsigned hi = (unsigned)f2bf(acc[nt][2] + bvv) | ((unsigned)f2bf(acc[nt][3] + bvv) << 16);
            *(uint2*)&Vtg[((size_t)b * HD + nn) * SEQ + s0] = make_uint2(lo, hi);
        }
    }
}

// ---------------------------------------------------------------------------
// attn_part: split-key flash attention, no online max (scores bounded),
// P = exp2(QK^T) with scale folded into Q.  Partials in bf16.
// grid (8, 144): x = batch (XCD-aligned: linear id ≡ batch mod 8, so each
// XCD's L2 caches one batch's K/V), y = compacted (c, qt) triangle.
// block 256 thr (4 waves x 16 q rows), <=4 K-iters.
// ---------------------------------------------------------------------------
__global__ __launch_bounds__(256)
void attn_part_kernel(const unsigned short* __restrict__ Qg,
                      const unsigned short* __restrict__ Kg,
                      const unsigned short* __restrict__ Vtg,
                      unsigned short* __restrict__ Opart,  // [2048][64][64] bf16
                      float* __restrict__ Lsum)            // [2048][64]
{
    const int b = blockIdx.x;
    // decode compacted triangle: for chunk c, valid qt in [4c, 31]
    int y = blockIdx.y, c = 0;
    while (y >= 32 - 4 * c) { y -= 32 - 4 * c; ++c; }
    const int qt = y + 4 * c;

    __shared__ unsigned short Ks[64][64];     // [key][d], swizzled (key r&7)
    __shared__ unsigned short Vs[64][64];     // [d][key], swizzled
    __shared__ unsigned short Ps[4][16][76];  // per-wave P, A layout [m][key]

    const int t    = threadIdx.x;
    const int w    = t >> 6;
    const int lane = t & 63;
    const int col  = lane & 15;
    const int quad = lane >> 4;
    const int q0w  = qt * QTILE + w * 16;
    const size_t gq = (size_t)b * SEQ + q0w;

    const bf16x8 aq0 = *(const bf16x8*)&Qg[(gq + col) * HD + quad * 8];
    const bf16x8 aq1 = *(const bf16x8*)&Qg[(gq + col) * HD + 32 + quad * 8];

    f32x4 oacc[4];
    #pragma unroll
    for (int n = 0; n < 4; ++n) oacc[n] = (f32x4){0.f, 0.f, 0.f, 0.f};
    float lpart[4] = {0.f, 0.f, 0.f, 0.f};   // per-lane partial denominators

    const int kbeg   = c * CHUNK;
    const int kend   = min((c + 1) * CHUNK, (qt + 1) * QTILE);
    const int ntiles = (kend - kbeg + 63) >> 6;

    const int r8 = lane >> 3, ch = lane & 7;
    const int swzr = (ch ^ r8) * 8;
    const unsigned short* kgb = Kg  + (size_t)b * SEQ * HD;
    const unsigned short* vgb = Vtg + (size_t)b * HD * SEQ;

    for (int it = 0; it < ntiles; ++it) {
        const int j0 = kbeg + it * 64;
        __syncthreads();
        // stage K (8 KB) + V^T (8 KB): 4 waves x 2 calls x 8 rows each
        #pragma unroll
        for (int ii = 0; ii < 2; ++ii) {
            const int rb = w * 16 + ii * 8;
            gld_lds16(&kgb[(size_t)(j0 + rb + r8) * HD + swzr], &Ks[rb][0]);
            gld_lds16(&vgb[(size_t)(rb + r8) * SEQ + j0 + swzr], &Vs[rb][0]);
        }
        __syncthreads();

        if (j0 <= q0w + 15) {   // wave-uniform: skip fully-masked tiles
            // scores (log2 domain: Q carries 0.125*log2e)
            f32x4 scv[4];
            #pragma unroll
            for (int nt = 0; nt < 4; ++nt) {
                const int sw0 = (quad ^ (col & 7)) * 8;
                const int sw1 = ((4 + quad) ^ (col & 7)) * 8;
                const bf16x8 bk0 = *(const bf16x8*)&Ks[nt * 16 + col][sw0];
                const bf16x8 bk1 = *(const bf16x8*)&Ks[nt * 16 + col][sw1];
                f32x4 s = __builtin_amdgcn_mfma_f32_16x16x32_bf16(aq0, bk0, (f32x4){0.f,0.f,0.f,0.f}, 0, 0, 0);
                s = __builtin_amdgcn_mfma_f32_16x16x32_bf16(aq1, bk1, s, 0, 0, 0);
                scv[nt] = s;
            }
            const bool needmask = (j0 + 63 > q0w);
            #pragma unroll
            for (int r = 0; r < 4; ++r) {
                const int row = q0w + quad * 4 + r;
                #pragma unroll
                for (int nt = 0; nt < 4; ++nt) {
                    float s = scv[nt][r];
                    if (needmask)
                        s = (j0 + nt * 16 + col <= row) ? s : -INFINITY;
                    const float p = fast_exp2(s);   // exp2(-inf) = 0 handles mask
                    lpart[r] += p;
                    Ps[w][quad * 4 + r][nt * 16 + col] = f2bf_hu(p);  // same-wave LDS
                }
            }
            // PV: O += P V
            #pragma unroll
            for (int ks = 0; ks < 2; ++ks) {
                const bf16x8 ap = *(const bf16x8*)&Ps[w][col][ks * 32 + quad * 8];
                const int fswz = ((ks * 4 + quad) ^ (col & 7)) * 8;
                #pragma unroll
                for (int n = 0; n < 4; ++n) {
                    const bf16x8 bv2 = *(const bf16x8*)&Vs[n * 16 + col][fswz];
                    oacc[n] = __builtin_amdgcn_mfma_f32_16x16x32_bf16(ap, bv2, oacc[n], 0, 0, 0);
                }
            }
        }
    }

    // deferred 16-lane reduction of the denominators (once per kernel)
    #pragma unroll
    for (int r = 0; r < 4; ++r) {
        #pragma unroll
        for (int off = 1; off < 16; off <<= 1)
            lpart[r] += __shfl_xor(lpart[r], off, 64);
    }

    // epilogue: un-normalized bf16 partials + fp32 denominators
    const int blk = (b * NQT + qt) * NCHUNK + c;
    unsigned short* Ob = Opart + (size_t)blk * (QTILE * HD);
    #pragma unroll
    for (int n = 0; n < 4; ++n)
        #pragma unroll
        for (int r = 0; r < 4; ++r)
            Ob[(w * 16 + quad * 4 + r) * HD + n * 16 + col] = f2bf(oacc[n][r]);
    if (col == 0) {
        float* lb = Lsum + (size_t)blk * QTILE;
        #pragma unroll
        for (int r = 0; r < 4; ++r)
            lb[w * 16 + quad * 4 + r] = lpart[r];
    }
}

// ---------------------------------------------------------------------------
// combine: out = sum(Opart) / sum(l).  1 thread per (row, 4 dims): uint2
// bf16 loads, float4 store.  grid 1024 x 256.
// ---------------------------------------------------------------------------
__global__ __launch_bounds__(256)
void combine_kernel(const unsigned short* __restrict__ Opart,
                    const float* __restrict__ Lsum,
                    float* __restrict__ out)
{
    const int gid = blockIdx.x * 256 + threadIdx.x;
    const int i   = gid >> 4;          // global row
    const int d4  = (gid & 15) * 4;    // dim group
    const int b   = i >> 11;
    const int s   = i & 2047;
    const int qt  = s >> 6;            // 64-row q tile
    const int r64 = s & 63;
    const int nc  = (s >> 8) + 1;      // chunks touching this row
    const int blk0 = (b * NQT + qt) * NCHUNK;

    float L = 0.f;
    float a0 = 0.f, a1 = 0.f, a2 = 0.f, a3 = 0.f;
    for (int cc = 0; cc < nc; ++cc) {
        L += Lsum[(size_t)(blk0 + cc) * QTILE + r64];
        const uint2 u = *(const uint2*)(Opart + (size_t)(blk0 + cc) * (QTILE * HD) + r64 * HD + d4);
        a0 += __uint_as_float(u.x << 16);
        a1 += __uint_as_float(u.x & 0xFFFF0000u);
        a2 += __uint_as_float(u.y << 16);
        a3 += __uint_as_float(u.y & 0xFFFF0000u);
    }
    const float rL = 1.0f / L;
    float4 o; o.x = a0 * rL; o.y = a1 * rL; o.z = a2 * rL; o.w = a3 * rL;
    *(float4*)&out[(size_t)i * HD + d4] = o;
}

// ---------------------------------------------------------------------------
extern "C" void kernel_launch(void* const* d_in, const int* in_sizes, int n_in,
                              void* d_out, int out_size, void* d_ws, size_t ws_size,
                              hipStream_t stream) {
    const float* x  = (const float*)d_in[0];
    const float* Wq = (const float*)d_in[1];
    const float* bq = (const float*)d_in[2];
    const float* Wk = (const float*)d_in[3];
    const float* bk = (const float*)d_in[4];
    const float* Wv = (const float*)d_in[5];
    const float* bv = (const float*)d_in[6];
    float* out = (float*)d_out;

    unsigned short* Wt    = (unsigned short*)d_ws;        // [3][64][1024] bf16
    unsigned short* Qg    = Wt + (size_t)3 * HD * DIM;    // [16384][64] bf16 (pre-scaled)
    unsigned short* Kg    = Qg + (size_t)NROWS * HD;      // [16384][64] bf16
    unsigned short* Vtg   = Kg + (size_t)NROWS * HD;      // [8][64][2048] bf16
    unsigned short* Opart = Vtg + (size_t)BATCH * HD * SEQ;               // [2048][64][64] bf16
    float* Lsum = (float*)(Opart + (size_t)BATCH * NQT * NCHUNK * QTILE * HD);  // [2048][64]

    prep_w_kernel<<<dim3(16, 3), 256, 0, stream>>>(Wq, Wk, Wv, Wt);
    qkv_mfma_kernel<<<dim3(NROWS / 64), 768, 0, stream>>>(x, Wt, bq, bk, bv, Qg, Kg, Vtg);
    attn_part_kernel<<<dim3(8, 144), 256, 0, stream>>>(Qg, Kg, Vtg, Opart, Lsum);
    combine_kernel<<<dim3(NROWS * 16 / 256), 256, 0, stream>>>(Opart, Lsum, out);
}

// Round 5
// 138.153 us; speedup vs baseline: 1.8133x; 1.0054x over previous
//
#include <hip/hip_runtime.h>
#include <math.h>

#define BATCH 8
#define SEQ   2048
#define DIM   1024
#define HD    64
#define NROWS (BATCH * SEQ)   // 16384
#define CHUNK 512
#define NCHUNK 4              // SEQ / CHUNK
#define QTILE 128             // q rows per attention block
#define NQT   (SEQ / QTILE)   // 16
#define QSCALE 0.1803368801f  // 0.125 * log2(e): folded into Q so P = exp2(QK^T)

typedef __attribute__((ext_vector_type(8))) short bf16x8;  // 8 bf16 = 4 VGPRs
typedef __attribute__((ext_vector_type(4))) float f32x4;

__device__ __forceinline__ unsigned short f2bf(float f) {
    unsigned u = __float_as_uint(f);
    u = (u + 0x7FFFu + ((u >> 16) & 1u)) >> 16;   // RNE
    return (unsigned short)u;
}
// cheap half-up rounding (2 ops)
__device__ __forceinline__ unsigned short f2bf_hu(float f) {
    return (unsigned short)((__float_as_uint(f) + 0x8000u) >> 16);
}
__device__ __forceinline__ float fast_exp2(float x) {
#if __has_builtin(__builtin_amdgcn_exp2f)
    return __builtin_amdgcn_exp2f(x);
#else
    return exp2f(x);
#endif
}

// async global -> LDS DMA, 16 B per lane.  LDS dest = wave-uniform base + lane*16.
__device__ __forceinline__ void gld_lds16(const void* g, void* l) {
    __builtin_amdgcn_global_load_lds(
        (const __attribute__((address_space(1))) void*)g,
        (__attribute__((address_space(3))) void*)l, 16, 0, 0);
}

// pack 8 fp32 -> 8 bf16 (half-up) as one uint4
__device__ __forceinline__ uint4 pack_bf16x8(float4 a, float4 b) {
    uint4 o;
    o.x = ((__float_as_uint(a.x) + 0x8000u) >> 16) | ((__float_as_uint(a.y) + 0x8000u) & 0xFFFF0000u);
    o.y = ((__float_as_uint(a.z) + 0x8000u) >> 16) | ((__float_as_uint(a.w) + 0x8000u) & 0xFFFF0000u);
    o.z = ((__float_as_uint(b.x) + 0x8000u) >> 16) | ((__float_as_uint(b.y) + 0x8000u) & 0xFFFF0000u);
    o.w = ((__float_as_uint(b.z) + 0x8000u) >> 16) | ((__float_as_uint(b.w) + 0x8000u) & 0xFFFF0000u);
    return o;
}

#define CFENCE() asm volatile("" ::: "memory")
#define RAW_BAR() do { CFENCE(); __builtin_amdgcn_s_barrier(); CFENCE(); } while (0)

// ---------------------------------------------------------------------------
// prep_w: Wt[mat][n][k] (bf16) <- W[k][n] (fp32).  grid (16,3), block 256.
// ---------------------------------------------------------------------------
__global__ __launch_bounds__(256)
void prep_w_kernel(const float* __restrict__ Wq, const float* __restrict__ Wk,
                   const float* __restrict__ Wv, unsigned short* __restrict__ Wt)
{
    const int mat = blockIdx.y;
    const float* __restrict__ W = (mat == 0) ? Wq : (mat == 1) ? Wk : Wv;
    const int k0 = blockIdx.x * 64;
    __shared__ float T[64][65];
    const int t = threadIdx.x;
    #pragma unroll
    for (int i = 0; i < 16; ++i) {
        const int idx = t + i * 256;
        T[idx >> 6][idx & 63] = W[(size_t)(k0 + (idx >> 6)) * HD + (idx & 63)];
    }
    __syncthreads();
    const int n = t >> 2;
    const int c = t & 3;
    union { unsigned short h[16]; uint4 v[2]; } buf;
    #pragma unroll
    for (int j = 0; j < 16; ++j) buf.h[j] = f2bf(T[c * 16 + j][n]);
    unsigned short* dst = Wt + ((size_t)mat * HD + n) * DIM + k0 + c * 16;
    *(uint4*)dst       = buf.v[0];
    *(uint4*)(dst + 8) = buf.v[1];
}

// ---------------------------------------------------------------------------
// qkv_mfma v4: tile 64 rows x 192 cols (grid 256), BK=64, double-buffered LDS
// (64 KB), raw s_barrier + counted vmcnt(2).  12 waves (768 thr):
// wave w -> mat = w>>2 (0=Q,1=K,2=V), row quarter wr = w&3.
// ---------------------------------------------------------------------------
__global__ __launch_bounds__(768)
void qkv_mfma_kernel(const float* __restrict__ x,
                     const unsigned short* __restrict__ Wt,
                     const float* __restrict__ bq, const float* __restrict__ bk,
                     const float* __restrict__ bv,
                     unsigned short* __restrict__ Qg,
                     unsigned short* __restrict__ Kg,
                     unsigned short* __restrict__ Vtg)
{
    __shared__ unsigned short Xs[2][64][64];    // 16 KB bf16, swizzled chunks (key r&7)
    __shared__ unsigned short Ws[2][192][64];   // 48 KB bf16, swizzled chunks (key r&7)

    const int t    = threadIdx.x;
    const int lane = t & 63;
    const int w    = t >> 6;         // 0..11
    const int col  = lane & 15;
    const int quad = lane >> 4;
    const int mat  = w >> 2;         // 0=Q, 1=K, 2=V
    const int wr   = w & 3;          // 16-row quarter
    const int row0 = blockIdx.x * 64;

    const int r8  = lane >> 3;       // W: row within an 8-row DMA call
    const int ch8 = lane & 7;        // W: 16B chunk within row (8 chunks)
    const int wswz = (ch8 ^ r8) * 8; // W source swizzle (rbase ≡ 0 mod 8)

    f32x4 acc[4];
    #pragma unroll
    for (int i = 0; i < 4; ++i) acc[i] = (f32x4){0.f, 0.f, 0.f, 0.f};

    // X staging: threads 0..511 own (row xr, 8-float chunk xc0)
    const int xr  = t >> 3;          // 0..63
    const int xc0 = t & 7;           // 0..7
    const float* __restrict__ xrow = &x[(size_t)(row0 + xr) * DIM];

    auto stageW = [&](int it, int bb) {   // 2 calls x 8 rows = 16 rows per wave
        const int k0 = it * 64;
        #pragma unroll
        for (int ii = 0; ii < 2; ++ii) {
            const int rbase = w * 16 + ii * 8;
            gld_lds16(&Wt[(size_t)(rbase + r8) * DIM + k0 + wswz], &Ws[bb][rbase][0]);
        }
    };
    auto computeT = [&](int bb) {
        #pragma unroll
        for (int ks = 0; ks < 2; ++ks) {
            const int fswz = ((ks * 4 + quad) ^ (col & 7)) * 8;
            const bf16x8 a = *(const bf16x8*)&Xs[bb][wr * 16 + col][fswz];
            #pragma unroll
            for (int nt = 0; nt < 4; ++nt) {
                const bf16x8 b = *(const bf16x8*)&Ws[bb][mat * 64 + nt * 16 + col][fswz];
                acc[nt] = __builtin_amdgcn_mfma_f32_16x16x32_bf16(a, b, acc[nt], 0, 0, 0);
            }
        }
    };

    // ---- prologue: stage tile 0; prefetch X(1) into regs ----
    float4 xa, xb;
    stageW(0, 0);
    if (t < 512) {
        xa = *(const float4*)(xrow + xc0 * 8);
        xb = *(const float4*)(xrow + xc0 * 8 + 4);
    }
    asm volatile("s_waitcnt vmcnt(0)" ::: "memory");
    if (t < 512) {
        *(uint4*)&Xs[0][xr][(xc0 ^ (xr & 7)) * 8] = pack_bf16x8(xa, xb);
        xa = *(const float4*)(xrow + 64 + xc0 * 8);
        xb = *(const float4*)(xrow + 64 + xc0 * 8 + 4);
    }

    int buf = 0;
    for (int it = 0; it < 16; ++it) {
        RAW_BAR();                    // [A] all waves done reading buf^1
        if (it < 15) {
            stageW(it + 1, buf ^ 1);  // prefetch next W tile (stays in flight)
            // drains W(it) + X-loads(it+1); leaves W(it+1) in flight
            asm volatile("s_waitcnt vmcnt(2)" ::: "memory");
            if (t < 512) {
                *(uint4*)&Xs[buf ^ 1][xr][(xc0 ^ (xr & 7)) * 8] = pack_bf16x8(xa, xb);
                if (it < 14) {
                    const float* xp = xrow + (it + 2) * 64;
                    xa = *(const float4*)(xp + xc0 * 8);
                    xb = *(const float4*)(xp + xc0 * 8 + 4);
                }
            }
        } else {
            asm volatile("s_waitcnt vmcnt(0)" ::: "memory");   // drain last W
        }
        RAW_BAR();                    // [D] tile `it` fully in LDS
        computeT(buf);                // ds_read + 8 MFMA per wave
        buf ^= 1;
    }

    // Epilogue.  C layout: col = lane&15, row = quad*4 + r.
    const int b    = row0 / SEQ;
    const int s0   = (row0 % SEQ) + wr * 16 + quad * 4;
    const int grow = row0 + wr * 16 + quad * 4;
    const float* __restrict__ bias = (mat == 0) ? bq : (mat == 1) ? bk : bv;
    const float oscale = (mat == 0) ? QSCALE : 1.0f;   // fold softmax scale into Q
    #pragma unroll
    for (int nt = 0; nt < 4; ++nt) {
        const int nn = nt * 16 + col;
        const float bvv = bias[nn];
        if (mat < 2) {
            unsigned short* __restrict__ o = (mat == 0) ? Qg : Kg;
            #pragma unroll
            for (int r = 0; r < 4; ++r)
                o[(size_t)(grow + r) * HD + nn] = f2bf((acc[nt][r] + bvv) * oscale);
        } else {
            const unsigned lo = (unsigned)f2bf(acc[nt][0] + bvv) | ((unsigned)f2bf(acc[nt][1] + bvv) << 16);
            const unsigned hi = (unsigned)f2bf(acc[nt][2] + bvv) | ((unsigned)f2bf(acc[nt][3] + bvv) << 16);
            *(uint2*)&Vtg[((size_t)b * HD + nn) * SEQ + s0] = make_uint2(lo, hi);
        }
    }
}

// ---------------------------------------------------------------------------
// attn_part v2: split-key flash attention, QTILE=128 (8 waves, 512 thr) so
// each staged K/V tile serves 2x the queries (total staging 66 -> 34 MB),
// CHUNK=512 (fewer partials: Opart 16.8 -> 8.4 MB), and K/V double-buffered
// with raw s_barrier + counted vmcnt(2) (1 K-DMA + 1 V-DMA per wave per
// tile) so staging latency hides under QK^T/softmax/PV of the previous tile.
// grid (8, 40): x = batch (XCD-aligned), y = compacted (c, qt) triangle.
// Max 8 tiles/block, avg 6.8 -- well balanced.  2 blocks/CU (52 KB LDS).
// ---------------------------------------------------------------------------
__global__ __launch_bounds__(512)
void attn_part_kernel(const unsigned short* __restrict__ Qg,
                      const unsigned short* __restrict__ Kg,
                      const unsigned short* __restrict__ Vtg,
                      unsigned short* __restrict__ Opart,  // [512][128][64] bf16
                      float* __restrict__ Lsum)            // [512][128]
{
    const int b = blockIdx.x;
    // decode compacted triangle: for chunk c, valid qt in [4c, 15]
    int y = blockIdx.y, c = 0;
    while (y >= NQT - 4 * c) { y -= NQT - 4 * c; ++c; }
    const int qt = y + 4 * c;

    __shared__ unsigned short Ks[2][64][64];  // [key][d], swizzled (key r&7)
    __shared__ unsigned short Vs[2][64][64];  // [d][key], swizzled
    __shared__ unsigned short Ps[8][16][76];  // per-wave P, A layout [m][key]

    const int t    = threadIdx.x;
    const int w    = t >> 6;         // 0..7
    const int lane = t & 63;
    const int col  = lane & 15;
    const int quad = lane >> 4;
    const int q0w  = qt * QTILE + w * 16;
    const size_t gq = (size_t)b * SEQ + q0w;

    const bf16x8 aq0 = *(const bf16x8*)&Qg[(gq + col) * HD + quad * 8];
    const bf16x8 aq1 = *(const bf16x8*)&Qg[(gq + col) * HD + 32 + quad * 8];

    f32x4 oacc[4];
    #pragma unroll
    for (int n = 0; n < 4; ++n) oacc[n] = (f32x4){0.f, 0.f, 0.f, 0.f};
    float lpart[4] = {0.f, 0.f, 0.f, 0.f};   // per-lane partial denominators

    const int kbeg   = c * CHUNK;
    const int kend   = min((c + 1) * CHUNK, (qt + 1) * QTILE);
    const int ntiles = (kend - kbeg + 63) >> 6;   // 2..8

    const int r8 = lane >> 3, ch = lane & 7;
    const int swzr = (ch ^ r8) * 8;
    const unsigned short* kgb = Kg  + (size_t)b * SEQ * HD;
    const unsigned short* vgb = Vtg + (size_t)b * HD * SEQ;

    // stage K tile (8 KB) + V^T tile (8 KB): 8 waves x (1 K + 1 V call) x 8 rows
    auto stageKV = [&](int it, int bb) {
        const int j0 = kbeg + it * 64;
        const int rb = w * 8;
        gld_lds16(&kgb[(size_t)(j0 + rb + r8) * HD + swzr], &Ks[bb][rb][0]);
        gld_lds16(&vgb[(size_t)(rb + r8) * SEQ + j0 + swzr], &Vs[bb][rb][0]);
    };

    stageKV(0, 0);   // prologue (completion enforced at it=0's vmcnt)

    int bufb = 0;
    for (int it = 0; it < ntiles; ++it) {
        RAW_BAR();                      // [A] readers of buf^1 done (prev compute)
        if (it + 1 < ntiles) {
            stageKV(it + 1, bufb ^ 1);  // prefetch next tile (stays in flight)
            // per-wave: 2 outstanding for tile it + 2 for it+1 (+Q loads at it=0)
            asm volatile("s_waitcnt vmcnt(2)" ::: "memory");
        } else {
            asm volatile("s_waitcnt vmcnt(0)" ::: "memory");
        }
        RAW_BAR();                      // [D] tile `it` fully in LDS
        const int j0 = kbeg + it * 64;

        if (j0 <= q0w + 15) {   // wave-uniform: skip fully-masked tiles
            // scores (log2 domain: Q carries 0.125*log2e)
            f32x4 scv[4];
            #pragma unroll
            for (int nt = 0; nt < 4; ++nt) {
                const int sw0 = (quad ^ (col & 7)) * 8;
                const int sw1 = ((4 + quad) ^ (col & 7)) * 8;
                const bf16x8 bk0 = *(const bf16x8*)&Ks[bufb][nt * 16 + col][sw0];
                const bf16x8 bk1 = *(const bf16x8*)&Ks[bufb][nt * 16 + col][sw1];
                f32x4 s = __builtin_amdgcn_mfma_f32_16x16x32_bf16(aq0, bk0, (f32x4){0.f,0.f,0.f,0.f}, 0, 0, 0);
                s = __builtin_amdgcn_mfma_f32_16x16x32_bf16(aq1, bk1, s, 0, 0, 0);
                scv[nt] = s;
            }
            const bool needmask = (j0 + 63 > q0w);
            #pragma unroll
            for (int r = 0; r < 4; ++r) {
                const int row = q0w + quad * 4 + r;
                #pragma unroll
                for (int nt = 0; nt < 4; ++nt) {
                    float s = scv[nt][r];
                    if (needmask)
                        s = (j0 + nt * 16 + col <= row) ? s : -INFINITY;
                    const float p = fast_exp2(s);   // exp2(-inf) = 0 handles mask
                    lpart[r] += p;
                    Ps[w][quad * 4 + r][nt * 16 + col] = f2bf_hu(p);  // same-wave LDS
                }
            }
            // PV: O += P V
            #pragma unroll
            for (int ks = 0; ks < 2; ++ks) {
                const bf16x8 ap = *(const bf16x8*)&Ps[w][col][ks * 32 + quad * 8];
                const int fswz = ((ks * 4 + quad) ^ (col & 7)) * 8;
                #pragma unroll
                for (int n = 0; n < 4; ++n) {
                    const bf16x8 bv2 = *(const bf16x8*)&Vs[bufb][n * 16 + col][fswz];
                    oacc[n] = __builtin_amdgcn_mfma_f32_16x16x32_bf16(ap, bv2, oacc[n], 0, 0, 0);
                }
            }
        }
        bufb ^= 1;
    }

    // deferred 16-lane reduction of the denominators (once per kernel)
    #pragma unroll
    for (int r = 0; r < 4; ++r) {
        #pragma unroll
        for (int off = 1; off < 16; off <<= 1)
            lpart[r] += __shfl_xor(lpart[r], off, 64);
    }

    // epilogue: un-normalized bf16 partials + fp32 denominators
    const int blk = (b * NQT + qt) * NCHUNK + c;
    unsigned short* Ob = Opart + (size_t)blk * (QTILE * HD);
    #pragma unroll
    for (int n = 0; n < 4; ++n)
        #pragma unroll
        for (int r = 0; r < 4; ++r)
            Ob[(w * 16 + quad * 4 + r) * HD + n * 16 + col] = f2bf(oacc[n][r]);
    if (col == 0) {
        float* lb = Lsum + (size_t)blk * QTILE + w * 16;
        #pragma unroll
        for (int r = 0; r < 4; ++r)
            lb[quad * 4 + r] = lpart[r];
    }
}

// ---------------------------------------------------------------------------
// combine: out = sum(Opart) / sum(l).  1 thread per (row, 4 dims): uint2
// bf16 loads, float4 store.  grid 1024 x 256.  nc <= 4 chunks per row.
// ---------------------------------------------------------------------------
__global__ __launch_bounds__(256)
void combine_kernel(const unsigned short* __restrict__ Opart,
                    const float* __restrict__ Lsum,
                    float* __restrict__ out)
{
    const int gid = blockIdx.x * 256 + threadIdx.x;
    const int i   = gid >> 4;          // global row
    const int d4  = (gid & 15) * 4;    // dim group
    const int b   = i >> 11;
    const int s   = i & 2047;
    const int qt  = s >> 7;            // 128-row q tile
    const int r   = s & 127;
    const int nc  = (s >> 9) + 1;      // chunks touching this row (<=4)
    const int blk0 = (b * NQT + qt) * NCHUNK;

    float L = 0.f;
    float a0 = 0.f, a1 = 0.f, a2 = 0.f, a3 = 0.f;
    for (int cc = 0; cc < nc; ++cc) {
        L += Lsum[(size_t)(blk0 + cc) * QTILE + r];
        const uint2 u = *(const uint2*)(Opart + (size_t)(blk0 + cc) * (QTILE * HD) + r * HD + d4);
        a0 += __uint_as_float(u.x << 16);
        a1 += __uint_as_float(u.x & 0xFFFF0000u);
        a2 += __uint_as_float(u.y << 16);
        a3 += __uint_as_float(u.y & 0xFFFF0000u);
    }
    const float rL = 1.0f / L;
    float4 o; o.x = a0 * rL; o.y = a1 * rL; o.z = a2 * rL; o.w = a3 * rL;
    *(float4*)&out[(size_t)i * HD + d4] = o;
}

// ---------------------------------------------------------------------------
extern "C" void kernel_launch(void* const* d_in, const int* in_sizes, int n_in,
                              void* d_out, int out_size, void* d_ws, size_t ws_size,
                              hipStream_t stream) {
    const float* x  = (const float*)d_in[0];
    const float* Wq = (const float*)d_in[1];
    const float* bq = (const float*)d_in[2];
    const float* Wk = (const float*)d_in[3];
    const float* bk = (const float*)d_in[4];
    const float* Wv = (const float*)d_in[5];
    const float* bv = (const float*)d_in[6];
    float* out = (float*)d_out;

    unsigned short* Wt    = (unsigned short*)d_ws;        // [3][64][1024] bf16
    unsigned short* Qg    = Wt + (size_t)3 * HD * DIM;    // [16384][64] bf16 (pre-scaled)
    unsigned short* Kg    = Qg + (size_t)NROWS * HD;      // [16384][64] bf16
    unsigned short* Vtg   = Kg + (size_t)NROWS * HD;      // [8][64][2048] bf16
    unsigned short* Opart = Vtg + (size_t)BATCH * HD * SEQ;               // [512][128][64] bf16
    float* Lsum = (float*)(Opart + (size_t)BATCH * NQT * NCHUNK * QTILE * HD);  // [512][128]

    prep_w_kernel<<<dim3(16, 3), 256, 0, stream>>>(Wq, Wk, Wv, Wt);
    qkv_mfma_kernel<<<dim3(NROWS / 64), 768, 0, stream>>>(x, Wt, bq, bk, bv, Qg, Kg, Vtg);
    attn_part_kernel<<<dim3(8, 40), 512, 0, stream>>>(Qg, Kg, Vtg, Opart, Lsum);
    combine_kernel<<<dim3(NROWS * 16 / 256), 256, 0, stream>>>(Opart, Lsum, out);
}